// Round 7
// baseline (324.390 us; speedup 1.0000x reference)
//
#include <hip/hip_runtime.h>
#include <stdint.h>

// GraphConv x5 on MI355X — round 26 (= round 25 resubmitted; infra failure).
// vs round 24 (FAILED absmax 3408): k_last was rewritten to 16 nodes/block
// (wave-per-4-nodes) but still launched at (NN+255)/256=391 blocks -> only
// 6256 nodes written, rest stayed memset-0. Fix: NN/16 = 6250 blocks.
// Everything else identical to round 24: k_aggfused issues BOTH 32-edge
// chunks' glds up front (8KB stage), A-masks under load shadow, vmcnt(4)
// -> consume A -> vmcnt(0) -> consume B (one exposed latency per 64 edges);
// k_last edge-parallel + shfl reduce.

#define NN 100000
#define NE 1600000
#define HID 64
#define NBKT 391            // ceil(NN/256), bucket = dst >> 8
#define CAP 8192            // padded bucket capacity (mean 4092, +64 sigma)
#define PMAX (NBKT * CAP)
#define TILE 4096
#define EPT 16              // TILE / 256
#define NTILE ((NE + TILE - 1) / TILE)   // 391

typedef __attribute__((ext_vector_type(8))) short bf16x8;
typedef __attribute__((ext_vector_type(4))) float f32x4;
typedef __attribute__((ext_vector_type(2))) unsigned int u32x2;
typedef __attribute__((ext_vector_type(4))) unsigned int u32x4;

__device__ __forceinline__ uint32_t rne_bf16(float v) {
    uint32_t u = __float_as_uint(v);
    return (u + 0x7fffu + ((u >> 16) & 1u)) >> 16;
}

// ---------------- CSR build ----------------

// tile-local LDS counting sort + coalesced segment write-out
__global__ __launch_bounds__(256) void k_bpart(const int* __restrict__ src,
                                               const int* __restrict__ dst,
                                               const float* __restrict__ w,
                                               int* __restrict__ bcur,
                                               int2* __restrict__ bpairs) {
    __shared__ int  hcnt[NBKT];      // count, then cursor
    __shared__ int  hoff[NBKT];      // local exclusive offset
    __shared__ int  hadj[NBKT];      // global base - local offset
    __shared__ int  sc0[512];
    __shared__ int  sc1[512];
    __shared__ int2 sT[TILE];        // 32 KB staged tile (bucket-sorted)
    __shared__ int  sAdj[TILE];      // 16 KB per-slot global adjust
    int tile0 = blockIdx.x * TILE;
    int t = threadIdx.x;
    for (int i = t; i < NBKT; i += 256) hcnt[i] = 0;
    __syncthreads();

    int   pk[EPT];
    int   bk[EPT];
    float wv[EPT];
    #pragma unroll
    for (int k = 0; k < EPT; k++) {
        int e = tile0 + t + k * 256;
        if (e < NE) {
            int d = dst[e];
            int b = d >> 8;
            pk[k] = (src[e] << 8) | (d & 255);
            wv[k] = w[e];
            bk[k] = b;
            atomicAdd(&hcnt[b], 1);
        } else {
            bk[k] = -1;
        }
    }
    __syncthreads();

    // inclusive scan of hcnt over 512 (padded) with ping-pong buffers
    sc0[t]       = (t < NBKT) ? hcnt[t] : 0;
    sc0[t + 256] = (t + 256 < NBKT) ? hcnt[t + 256] : 0;
    __syncthreads();
    int* cur = sc0;
    int* oth = sc1;
    for (int off = 1; off < 512; off <<= 1) {
        int v0 = cur[t]       + ((t       >= off) ? cur[t - off]       : 0);
        int v1 = cur[t + 256] + ((t + 256 >= off) ? cur[t + 256 - off] : 0);
        oth[t] = v0;
        oth[t + 256] = v1;
        __syncthreads();
        int* tmp = cur; cur = oth; oth = tmp;
    }
    for (int i = t; i < NBKT; i += 256) {
        int c = hcnt[i];
        int excl = cur[i] - c;
        hoff[i] = excl;
        int gbase = c ? atomicAdd(&bcur[i], c) : 0;
        hadj[i] = gbase - excl;
        hcnt[i] = 0;                 // reuse as local cursor
    }
    __syncthreads();

    // scatter into LDS (bucket-sorted order)
    #pragma unroll
    for (int k = 0; k < EPT; k++) {
        if (bk[k] >= 0) {
            int b = bk[k];
            int pos = hoff[b] + atomicAdd(&hcnt[b], 1);
            sT[pos] = make_int2(pk[k], __float_as_int(wv[k]));
            sAdj[pos] = hadj[b];
        }
    }
    __syncthreads();

    // linear write-out: consecutive slots in a bucket run -> consecutive
    // global addresses (coalesced bursts)
    int n = NE - tile0; if (n > TILE) n = TILE;
    for (int j = t; j < n; j += 256)
        bpairs[sAdj[j] + j] = sT[j];
}

// one block per bucket: stage bucket in LDS, then LDS counting sort.
__global__ __launch_bounds__(256) void k_bcsr(const int* __restrict__ bcur,
                                              const int2* __restrict__ bpairs,
                                              int* __restrict__ offs,
                                              int* __restrict__ ends,
                                              uint32_t* __restrict__ pairs) {
    __shared__ int2 sE[CAP];        // 64 KB bucket stage
    __shared__ int cnt[256];
    __shared__ int scn[256];
    __shared__ int cur[256];
    int k = blockIdx.x, t = threadIdx.x;
    int base = k * CAP;
    int scnt = bcur[k] - base;
    cnt[t] = 0;
    __syncthreads();
    for (int j = t; j < scnt; j += 256) {
        int2 q = bpairs[base + j];
        sE[j] = q;
        atomicAdd(&cnt[q.x & 255], 1);
    }
    __syncthreads();
    int v = cnt[t], acc = v;
    scn[t] = v;
    __syncthreads();
    for (int off = 1; off < 256; off <<= 1) {
        int u = (t >= off) ? scn[t - off] : 0;
        __syncthreads();
        acc += u;
        scn[t] = acc;
        __syncthreads();
    }
    int excl = acc - v;
    cur[t] = excl;
    int d = (k << 8) + t;
    if (d < NN) {
        offs[d] = base + excl;
        ends[d] = base + excl + v;
    }
    __syncthreads();
    for (int j = t; j < scnt; j += 256) {
        int2 q = sE[j];
        int pos = base + atomicAdd(&cur[q.x & 255], 1);
        uint32_t wb = rne_bf16(__int_as_float(q.y)) & 0x7fffu;   // w >= 0
        pairs[pos] = (wb << 17) | (uint32_t)(q.x >> 8);
    }
}

// ---------------- weight hi/lo split (+ bucket cursor init) ----------------

__global__ __launch_bounds__(256) void k_wsplit(const float* __restrict__ Wrel_mid,
                                                const float* __restrict__ Wroot_mid,
                                                uint16_t* __restrict__ WgH,
                                                uint16_t* __restrict__ WgL,
                                                uint16_t* __restrict__ WrH,
                                                uint16_t* __restrict__ WrL,
                                                int* __restrict__ bcur) {
    int i = blockIdx.x * blockDim.x + threadIdx.x;
    if (i < NBKT) bcur[i] = i * CAP;
    if (i >= 3 * 4096) return;
    float a = Wrel_mid[i];
    uint32_t ah = rne_bf16(a);
    float al = a - __uint_as_float(ah << 16);
    WgH[i] = (uint16_t)ah;
    WgL[i] = (uint16_t)rne_bf16(al);
    float b = Wroot_mid[i];
    uint32_t bh = rne_bf16(b);
    float bl = b - __uint_as_float(bh << 16);
    WrH[i] = (uint16_t)bh;
    WrL[i] = (uint16_t)rne_bf16(bl);
}

// ---------------- shared epilogue: 16-node h (LDS) -> G,R via LDS tiles ----

__device__ __forceinline__ void mfma_epilogue(
        int lane, int w, const uint32_t* sH,
        const uint16_t* __restrict__ WgH, const uint16_t* __restrict__ WgL,
        const uint16_t* __restrict__ WrH, const uint16_t* __restrict__ WrL,
        const float* __restrict__ brel,
        uint16_t* sG, uint16_t* sR) {
    int row = lane & 15;
    int quad = lane >> 4;
    int kb = quad * 8;
    bf16x8 ah0 = *(const bf16x8*)&sH[row * 36 + quad * 4];
    bf16x8 ah1 = *(const bf16x8*)&sH[row * 36 + 16 + quad * 4];
    int oc = w * 16 + row;
    {
        bf16x8 bh0 = *(const bf16x8*)&WgH[oc * 64 + kb];
        bf16x8 bh1 = *(const bf16x8*)&WgH[oc * 64 + 32 + kb];
        bf16x8 bl0 = *(const bf16x8*)&WgL[oc * 64 + kb];
        bf16x8 bl1 = *(const bf16x8*)&WgL[oc * 64 + 32 + kb];
        f32x4 acc = {0.f, 0.f, 0.f, 0.f};
        acc = __builtin_amdgcn_mfma_f32_16x16x32_bf16(ah0, bh0, acc, 0, 0, 0);
        acc = __builtin_amdgcn_mfma_f32_16x16x32_bf16(ah1, bh1, acc, 0, 0, 0);
        acc = __builtin_amdgcn_mfma_f32_16x16x32_bf16(ah0, bl0, acc, 0, 0, 0);
        acc = __builtin_amdgcn_mfma_f32_16x16x32_bf16(ah1, bl1, acc, 0, 0, 0);
        #pragma unroll
        for (int r = 0; r < 4; r++)
            sG[(quad * 4 + r) * 68 + oc] = (uint16_t)rne_bf16(acc[r]);
    }
    {
        bf16x8 bh0 = *(const bf16x8*)&WrH[oc * 64 + kb];
        bf16x8 bh1 = *(const bf16x8*)&WrH[oc * 64 + 32 + kb];
        bf16x8 bl0 = *(const bf16x8*)&WrL[oc * 64 + kb];
        bf16x8 bl1 = *(const bf16x8*)&WrL[oc * 64 + 32 + kb];
        float bias = brel[oc];
        f32x4 acc = {bias, bias, bias, bias};
        acc = __builtin_amdgcn_mfma_f32_16x16x32_bf16(ah0, bh0, acc, 0, 0, 0);
        acc = __builtin_amdgcn_mfma_f32_16x16x32_bf16(ah1, bh1, acc, 0, 0, 0);
        acc = __builtin_amdgcn_mfma_f32_16x16x32_bf16(ah0, bl0, acc, 0, 0, 0);
        acc = __builtin_amdgcn_mfma_f32_16x16x32_bf16(ah1, bl1, acc, 0, 0, 0);
        #pragma unroll
        for (int r = 0; r < 4; r++)
            sR[(quad * 4 + r) * 68 + oc] = (uint16_t)rne_bf16(acc[r]);
    }
}

__device__ __forceinline__ void epilogue_writeout(
        int tid, int blk16, const uint16_t* sG, const uint16_t* sR,
        uint16_t* __restrict__ Gout, uint16_t* __restrict__ Rout) {
    const uint32_t* sGd = (const uint32_t*)sG;   // stride 34 dwords/node
    const uint32_t* sRd = (const uint32_t*)sR;
    uint32_t* Gd = (uint32_t*)Gout;
    uint32_t* Rd = (uint32_t*)Rout;
    #pragma unroll
    for (int it = 0; it < 2; it++) {
        int idx = it * 256 + tid;
        int nd = idx >> 5, col = idx & 31;
        Gd[(blk16 + nd) * 32 + col] = sGd[nd * 34 + col];
        Rd[(blk16 + nd) * 32 + col] = sRd[nd * 34 + col];
    }
}

// ---------------- layers ----------------

// layer 0 (fused): edge-parallel aggregation (all waves, shfl reduce), then
// h0 = relu(...) staged in LDS, MFMA epilogue -> G1,R1.
__global__ __launch_bounds__(256) void k_l0pre(
        const int* __restrict__ offs, const int* __restrict__ ends,
        const uint32_t* __restrict__ pairs, const float* __restrict__ x,
        const float* __restrict__ Wrel0, const float* __restrict__ brel0,
        const float* __restrict__ Wroot0,
        const uint16_t* __restrict__ WgH, const uint16_t* __restrict__ WgL,
        const uint16_t* __restrict__ WrH, const uint16_t* __restrict__ WrL,
        const float* __restrict__ brel,
        uint16_t* __restrict__ Gout, uint16_t* __restrict__ Rout) {
    __shared__ uint32_t sH[16 * 36];
    __shared__ uint16_t sG[16 * 68];
    __shared__ uint16_t sR[16 * 68];
    int c = threadIdx.x & 63;
    int w = threadIdx.x >> 6;
    int blk16 = blockIdx.x * 16;
    float agg[4];
    #pragma unroll
    for (int t = 0; t < 4; t++) {
        int node = blk16 + w * 4 + t;
        int b = offs[node], e = ends[node];
        float pp = 0.f;
        for (int j = b + c; j < e; j += 64) {
            uint32_t r = pairs[j];
            pp += __uint_as_float((r >> 17) << 16) * x[r & 0x1ffffu];
        }
        for (int o = 32; o > 0; o >>= 1) pp += __shfl_down(pp, o, 64);
        agg[t] = __shfl(pp, 0, 64);
    }
    float wr = Wrel0[c], br = brel0[c], wo = Wroot0[c];
    #pragma unroll
    for (int t = 0; t < 4; t++) {
        int node = blk16 + w * 4 + t;
        float v = agg[t] * wr + br + x[node] * wo;
        v = v > 0.f ? v : 0.f;
        uint32_t hb = rne_bf16(v);
        uint32_t pn = (uint32_t)__shfl_xor((int)hb, 1, 64);
        if (!(c & 1)) sH[(w * 4 + t) * 36 + (c >> 1)] = hb | (pn << 16);
    }
    __syncthreads();
    mfma_epilogue(c, w, sH, WgH, WgL, WrH, WrL, brel, sG, sR);
    __syncthreads();
    epilogue_writeout((int)threadIdx.x, blk16, sG, sR, Gout, Rout);
}

// transpose-read, byte-addressed: column = addr bits[6:3], subtile = the
// 128B-aligned base; lane reads bytes (addr&~127) + ((addr>>3)&15)*2 + 32*j
#define TRRA(dst, off) \
    asm volatile("ds_read_b64_tr_b16 %0, %1 offset:" #off \
                 : "=v"(dst) : "v"(trbA))
#define TRRB(dst, off) \
    asm volatile("ds_read_b64_tr_b16 %0, %1 offset:" #off \
                 : "=v"(dst) : "v"(trbB))

// Fused aggregation + pre-transform, MFMA consume, depth-1 pipelined
// staging: both 32-edge chunks' glds issued up front, A-masks under load
// shadow, vmcnt(4) -> consume A -> vmcnt(0) -> consume B.
template <bool LAST>
__global__ __launch_bounds__(256, 4) void k_aggfused(
        const int* __restrict__ offs, const int* __restrict__ ends,
        const uint32_t* __restrict__ pairs,
        const uint16_t* __restrict__ Gb, const uint16_t* __restrict__ Rb,
        const uint16_t* __restrict__ WgH, const uint16_t* __restrict__ WgL,
        const uint16_t* __restrict__ WrH, const uint16_t* __restrict__ WrL,
        const float* __restrict__ brel,
        uint16_t* __restrict__ Gout, uint16_t* __restrict__ Rout,
        const float* __restrict__ WrelL, const float* __restrict__ WrootL,
        float* __restrict__ sarr, float* __restrict__ rarr) {
    __shared__ uint32_t sH[16 * 36];
    // 4 waves x 8KB gather stage (two 4KB chunk buffers, subtiled layout);
    // dead before the MFMA epilogue, so sG/sR overlay it. 35072 B total ->
    // 4 blocks/CU (16 waves).
    __shared__ __align__(128) char smem[32768];
    int c = threadIdx.x & 63;
    int w = threadIdx.x >> 6;
    int blk16 = blockIdx.x * 16;
    int n0 = blk16 + w * 4;
    int ov = 0;
    if (c < 4) ov = offs[n0 + c];
    else if (c == 4) ov = ends[n0 + 3];
    int bnd[5];
    bnd[0] = __builtin_amdgcn_readlane(ov, 0);
    bnd[1] = __builtin_amdgcn_readlane(ov, 1);
    bnd[2] = __builtin_amdgcn_readlane(ov, 2);
    bnd[3] = __builtin_amdgcn_readlane(ov, 3);
    bnd[4] = __builtin_amdgcn_readlane(ov, 4);

    // ---- per-lane constants ----
    int arow  = c & 15;                       // A/C row (node 0..3 valid)
    int kq    = (c >> 4) * 8;                 // MFMA k-base for this quad
    // staging permutation: lane L fetches edge eprm of its 8-edge group,
    // cols c0 = ((L>>3)&3)*16 + (L&1)*8 so linear LDS dest == subtiled
    // layout: byte(e,col) = (e>>3)*1024 + ((e>>2)&1)*512 + (col>>4)*128
    //                      + (e&3)*32 + (col&15)*2
    int eprm  = ((c >> 5) << 2) | ((c >> 1) & 3);
    int lbyte = ((c >> 3) & 3) * 32 + (c & 1) * 16;
    char* stg = smem + w * 8192;              // chunk A: stg, chunk B: +4096
    uint32_t stgOff = (uint32_t)(uintptr_t)
        (__attribute__((address_space(3))) char*)stg;
    uint32_t trbA = stgOff + ((uint32_t)(c >> 4) << 10)
                          + ((uint32_t)(c & 15) << 3);
    uint32_t trbB = trbA + 4096;

    // per-lane segment bounds for the A mask
    int blo = bnd[0], bhi = bnd[1];
    if (arow == 1) { blo = bnd[1]; bhi = bnd[2]; }
    if (arow == 2) { blo = bnd[2]; bhi = bnd[3]; }
    if (arow == 3) { blo = bnd[3]; bhi = bnd[4]; }
    if (arow >= 4) { blo = 0;      bhi = 0;      }
    uint32_t wid = (uint32_t)(bhi - blo);

    // C-init = root rows (Rb already holds Wroot*h + brel), redistributed
    // from the coalesced per-col layout into the C fragment layout.
    f32x4 acc16[4];
    {
        int ur[4];
        #pragma unroll
        for (int t = 0; t < 4; t++) ur[t] = (int)(uint32_t)Rb[(n0 + t) * 64 + c];
        #pragma unroll
        for (int nb = 0; nb < 4; nb++) {
            int idx = (nb * 16 + (c & 15)) * 4;
            f32x4 ci;
            #pragma unroll
            for (int t = 0; t < 4; t++) {
                uint32_t rv = (uint32_t)__builtin_amdgcn_ds_bpermute(idx, ur[t]);
                ci[t] = __uint_as_float(rv << 16);
            }
            acc16[nb] = ci;
        }
    }

    const char* gbase = (const char*)Gb;
    // prologue pairs load (unconditional, clamped; lanes past end masked 0)
    int j0 = bnd[0] + c; if (j0 > PMAX - 1) j0 = PMAX - 1;
    uint32_t praw = pairs[j0];
    uint32_t p = (bnd[0] + c < bnd[4]) ? praw : 0;

    for (int cb = bnd[0]; cb < bnd[4]; cb += 64) {
        // next super-chunk pairs (unconditional, clamped -> constant vmcnt)
        int jn = cb + 64 + c; if (jn > PMAX - 1) jn = PMAX - 1;
        uint32_t pr2 = pairs[jn];                               // vmem 1
        // ISSUE chunk A glds (edges 0-31)                       vmem 2-5
        #pragma unroll
        for (int i = 0; i < 4; i++) {
            uint32_t r = (uint32_t)__builtin_amdgcn_ds_bpermute(
                (eprm + i * 8) * 4, (int)p);
            uint32_t voff = ((r & 0x1ffffu) << 7) + (uint32_t)lbyte;
            __builtin_amdgcn_global_load_lds(
                (const __attribute__((address_space(1))) void*)(gbase + voff),
                (__attribute__((address_space(3))) void*)(stg + i * 1024),
                16, 0, 0);
        }
        // ISSUE chunk B glds (edges 32-63)                      vmem 6-9
        #pragma unroll
        for (int i = 0; i < 4; i++) {
            uint32_t r = (uint32_t)__builtin_amdgcn_ds_bpermute(
                (32 + eprm + i * 8) * 4, (int)p);
            uint32_t voff = ((r & 0x1ffffu) << 7) + (uint32_t)lbyte;
            __builtin_amdgcn_global_load_lds(
                (const __attribute__((address_space(1))) void*)(gbase + voff),
                (__attribute__((address_space(3))) void*)(stg + 4096 + i * 1024),
                16, 0, 0);
        }
        // A fragments for BOTH chunks, under the load shadow
        uint32_t mA[8], mB[8];
        int dbA = cb + kq - blo;
        int dbB = cb + 32 + kq - blo;
        #pragma unroll
        for (int q = 0; q < 8; q++) {
            uint32_t rq = (uint32_t)__builtin_amdgcn_ds_bpermute(
                (kq + q) * 4, (int)p);
            mA[q] = ((uint32_t)(dbA + q) < wid) ? (rq >> 17) : 0u;
        }
        #pragma unroll
        for (int q = 0; q < 8; q++) {
            uint32_t rq = (uint32_t)__builtin_amdgcn_ds_bpermute(
                (32 + kq + q) * 4, (int)p);
            mB[q] = ((uint32_t)(dbB + q) < wid) ? (rq >> 17) : 0u;
        }
        u32x4 aav = { mA[0] | (mA[1] << 16), mA[2] | (mA[3] << 16),
                      mA[4] | (mA[5] << 16), mA[6] | (mA[7] << 16) };
        u32x4 abv = { mB[0] | (mB[1] << 16), mB[2] | (mB[3] << 16),
                      mB[4] | (mB[5] << 16), mB[6] | (mB[7] << 16) };
        bf16x8 afA = __builtin_bit_cast(bf16x8, aav);
        bf16x8 afB = __builtin_bit_cast(bf16x8, abv);
        // wait: pr2 + chunk A complete; chunk B (4) still in flight
        asm volatile("s_waitcnt vmcnt(4)" ::: "memory");
        {
            u32x2 tb0, tb1, tb2, tb3, tb4, tb5, tb6, tb7;
            TRRA(tb0, 0);   TRRA(tb1, 512);
            TRRA(tb2, 128); TRRA(tb3, 640);
            TRRA(tb4, 256); TRRA(tb5, 768);
            TRRA(tb6, 384); TRRA(tb7, 896);
            asm volatile("s_waitcnt lgkmcnt(0)" ::: "memory");
            __builtin_amdgcn_sched_barrier(0);
            u32x4 bb0 = { tb0.x, tb0.y, tb1.x, tb1.y };
            acc16[0] = __builtin_amdgcn_mfma_f32_16x16x32_bf16(
                afA, __builtin_bit_cast(bf16x8, bb0), acc16[0], 0, 0, 0);
            u32x4 bb1 = { tb2.x, tb2.y, tb3.x, tb3.y };
            acc16[1] = __builtin_amdgcn_mfma_f32_16x16x32_bf16(
                afA, __builtin_bit_cast(bf16x8, bb1), acc16[1], 0, 0, 0);
            u32x4 bb2 = { tb4.x, tb4.y, tb5.x, tb5.y };
            acc16[2] = __builtin_amdgcn_mfma_f32_16x16x32_bf16(
                afA, __builtin_bit_cast(bf16x8, bb2), acc16[2], 0, 0, 0);
            u32x4 bb3 = { tb6.x, tb6.y, tb7.x, tb7.y };
            acc16[3] = __builtin_amdgcn_mfma_f32_16x16x32_bf16(
                afA, __builtin_bit_cast(bf16x8, bb3), acc16[3], 0, 0, 0);
        }
        // wait: chunk B complete
        asm volatile("s_waitcnt vmcnt(0)" ::: "memory");
        {
            u32x2 tb0, tb1, tb2, tb3, tb4, tb5, tb6, tb7;
            TRRB(tb0, 0);   TRRB(tb1, 512);
            TRRB(tb2, 128); TRRB(tb3, 640);
            TRRB(tb4, 256); TRRB(tb5, 768);
            TRRB(tb6, 384); TRRB(tb7, 896);
            asm volatile("s_waitcnt lgkmcnt(0)" ::: "memory");
            __builtin_amdgcn_sched_barrier(0);
            u32x4 bb0 = { tb0.x, tb0.y, tb1.x, tb1.y };
            acc16[0] = __builtin_amdgcn_mfma_f32_16x16x32_bf16(
                afB, __builtin_bit_cast(bf16x8, bb0), acc16[0], 0, 0, 0);
            u32x4 bb1 = { tb2.x, tb2.y, tb3.x, tb3.y };
            acc16[1] = __builtin_amdgcn_mfma_f32_16x16x32_bf16(
                afB, __builtin_bit_cast(bf16x8, bb1), acc16[1], 0, 0, 0);
            u32x4 bb2 = { tb4.x, tb4.y, tb5.x, tb5.y };
            acc16[2] = __builtin_amdgcn_mfma_f32_16x16x32_bf16(
                afB, __builtin_bit_cast(bf16x8, bb2), acc16[2], 0, 0, 0);
            u32x4 bb3 = { tb6.x, tb6.y, tb7.x, tb7.y };
            acc16[3] = __builtin_amdgcn_mfma_f32_16x16x32_bf16(
                afB, __builtin_bit_cast(bf16x8, bb3), acc16[3], 0, 0, 0);
        }
        p = (cb + 64 + c < bnd[4]) ? pr2 : 0;
    }

    if (!LAST) {
        // lanes 0-15 hold C rows 0-3 (regs t) for cols nb*16+(c&15)
        #pragma unroll
        for (int t = 0; t < 4; t++) {
            #pragma unroll
            for (int nb = 0; nb < 4; nb++) {
                float v = acc16[nb][t];
                v = v > 0.f ? v : 0.f;
                uint32_t hb = rne_bf16(v);
                uint32_t pn2 = (uint32_t)__shfl_xor((int)hb, 1, 64);
                if (!(c & 1) && c < 16)
                    sH[(w * 4 + t) * 36 + nb * 8 + (c >> 1)] = hb | (pn2 << 16);
            }
        }
        __syncthreads();
        uint16_t* sG = (uint16_t*)smem;           // overlay on dead stage
        uint16_t* sR = (uint16_t*)(smem + 2176);
        mfma_epilogue(c, w, sH, WgH, WgL, WrH, WrL, brel, sG, sR);
        __syncthreads();
        epilogue_writeout((int)threadIdx.x, blk16, sG, sR, Gout, Rout);
    } else {
        float wl[4], wo[4];
        #pragma unroll
        for (int nb = 0; nb < 4; nb++) {
            wl[nb] = WrelL[nb * 16 + (c & 15)];
            wo[nb] = WrootL[nb * 16 + (c & 15)];
        }
        #pragma unroll
        for (int t = 0; t < 4; t++) {
            float pa = 0.f, pr = 0.f;
            #pragma unroll
            for (int nb = 0; nb < 4; nb++) {
                float v = acc16[nb][t];
                v = v > 0.f ? v : 0.f;
                pa += v * wl[nb];
                pr += v * wo[nb];
            }
            #pragma unroll
            for (int o = 8; o > 0; o >>= 1) {
                pa += __shfl_down(pa, o, 64);
                pr += __shfl_down(pr, o, 64);
            }
            if (c == 0) { sarr[n0 + t] = pa; rarr[n0 + t] = pr; }
        }
    }
}

// final edge pass: wave-per-4-nodes edge-parallel gather + shfl reduce
__global__ __launch_bounds__(256) void k_last(
        const int* __restrict__ offs, const int* __restrict__ ends,
        const uint32_t* __restrict__ pairs,
        const float* __restrict__ sarr, const float* __restrict__ rarr,
        const float* __restrict__ brelL, float* __restrict__ out) {
    int c = threadIdx.x & 63;
    int w = threadIdx.x >> 6;
    int blk16 = blockIdx.x * 16;
    float b0 = brelL[0];
    #pragma unroll
    for (int t = 0; t < 4; t++) {
        int node = blk16 + w * 4 + t;
        int b = offs[node], e = ends[node];
        float pp = 0.f;
        for (int j = b + c; j < e; j += 64) {
            uint32_t r = pairs[j];
            pp += __uint_as_float((r >> 17) << 16) * sarr[r & 0x1ffffu];
        }
        #pragma unroll
        for (int o = 32; o > 0; o >>= 1) pp += __shfl_down(pp, o, 64);
        if (c == 0) out[node] = pp + rarr[node] + b0;
    }
}

extern "C" void kernel_launch(void* const* d_in, const int* in_sizes, int n_in,
                              void* d_out, int out_size, void* d_ws, size_t ws_size,
                              hipStream_t stream) {
    const float* x        = (const float*)d_in[0];
    const int*   ei       = (const int*)d_in[1];
    const float* ew       = (const float*)d_in[2];
    const float* Wrel0    = (const float*)d_in[3];
    const float* brel0    = (const float*)d_in[4];
    const float* Wroot0   = (const float*)d_in[5];
    const float* Wrel_mid = (const float*)d_in[6];
    const float* brel_mid = (const float*)d_in[7];
    const float* Wroot_mid= (const float*)d_in[8];
    const float* WrelL    = (const float*)d_in[9];
    const float* brelL    = (const float*)d_in[10];
    const float* WrootL   = (const float*)d_in[11];
    float* out = (float*)d_out;

    const int* src  = ei;
    const int* dstp = ei + NE;

    char* w = (char*)d_ws;
    size_t o = 0;
    auto alloc = [&](size_t b) -> void* {
        void* r = (void*)(w + o);
        o += (b + 255) & ~(size_t)255;
        return r;
    };
    int*      offs  = (int*)alloc((size_t)NN * 4);
    int*      ends  = (int*)alloc((size_t)NN * 4);
    int*      bcur  = (int*)alloc((size_t)NBKT * 4);
    uint16_t* WgH   = (uint16_t*)alloc((size_t)3 * 4096 * 2);
    uint16_t* WgL   = (uint16_t*)alloc((size_t)3 * 4096 * 2);
    uint16_t* WrH   = (uint16_t*)alloc((size_t)3 * 4096 * 2);
    uint16_t* WrL   = (uint16_t*)alloc((size_t)3 * 4096 * 2);
    float*    sarr  = (float*)alloc((size_t)NN * 4);
    float*    rarr  = (float*)alloc((size_t)NN * 4);
    uint32_t* pairs = (uint32_t*)alloc((size_t)NBKT * CAP * 4);  // 12.8 MB padded
    uint16_t* GbA   = (uint16_t*)alloc((size_t)NN * HID * 2);    // 12.8 MB
    uint16_t* RbA   = (uint16_t*)alloc((size_t)NN * HID * 2);
    uint16_t* GbB   = (uint16_t*)alloc((size_t)NN * HID * 2);    // GbB/RbB contiguous
    uint16_t* RbB   = (uint16_t*)alloc((size_t)NN * HID * 2);
    (void)RbB;
    // bpairs (NBKT*CAP*8B = 25.6MB) aliases GbB+RbB (contiguous; dead before
    // mid layer 1 writes set B)
    int2*  bpairs = (int2*)GbB;

    // weight split + bucket cursor init (one launch)
    k_wsplit<<<(3 * 4096 + 255) / 256, 256, 0, stream>>>(
        Wrel_mid, Wroot_mid, WgH, WgL, WrH, WrL, bcur);

    // CSR build (padded buckets)
    k_bpart<<<NTILE, 256, 0, stream>>>(src, dstp, ew, bcur, bpairs);
    k_bcsr<<<NBKT, 256, 0, stream>>>(bcur, bpairs, offs, ends, pairs);

    // layer 0 (agg + transform + pre) -> G1,R1 (set A)
    k_l0pre<<<NN / 16, 256, 0, stream>>>(
        offs, ends, pairs, x, Wrel0, brel0, Wroot0,
        WgH, WgL, WrH, WrL, brel_mid, GbA, RbA);

    // mid layer 1: consume set A, produce set B (weights index 1)
    k_aggfused<false><<<NN / 16, 256, 0, stream>>>(
        offs, ends, pairs, GbA, RbA,
        WgH + 4096, WgL + 4096, WrH + 4096, WrL + 4096, brel_mid + HID,
        GbB, RbB, WrelL, WrootL, sarr, rarr);
    // mid layer 2: consume set B, produce set A (weights index 2)
    k_aggfused<false><<<NN / 16, 256, 0, stream>>>(
        offs, ends, pairs, GbB, RbB,
        WgH + 2 * 4096, WgL + 2 * 4096, WrH + 2 * 4096, WrL + 2 * 4096,
        brel_mid + 2 * HID, GbA, RbA, WrelL, WrootL, sarr, rarr);
    // mid layer 3 (LAST): consume set A, produce s/r scalars
    k_aggfused<true><<<NN / 16, 256, 0, stream>>>(
        offs, ends, pairs, GbA, RbA,
        WgH, WgL, WrH, WrL, brel_mid,
        GbB, RbB, WrelL, WrootL, sarr, rarr);

    // final edge pass on scalars (16 nodes/block -> NN/16 blocks)
    k_last<<<NN / 16, 256, 0, stream>>>(offs, ends, pairs, sarr, rarr, brelL, out);
}

// Round 8
// 306.623 us; speedup vs baseline: 1.0579x; 1.0579x over previous
//
#include <hip/hip_runtime.h>
#include <stdint.h>

// GraphConv x5 on MI355X — round 27.
// vs round 26 (324.4us; k_aggfused flat at ~60us across 4 schedule variants):
// mean degree 16 -> 4-node waves run ONE main-loop iteration; the per-wave
// fixed chain (offs->pairs->C-init->drain->sync->epilogue) dominates and is
// invariant to scheduling. Fix: 16 nodes/wave (64/block, grid 1563) using
// ALL 16 C rows (A rows 4-15 were masked waste). 4x amortization of fixed
// costs; per-lane bounds now direct offs/ends loads (no readlanes); C-init
// direct Rb loads (no bpermutes); epilogue wave-private (C holds all 16
// nodes; sH/sG/sR overlay the dead gather stage; NO __syncthreads at all).
// LDS 4x8KB exactly -> 5 blocks/CU.

#define NN 100000
#define NE 1600000
#define HID 64
#define NBKT 391            // ceil(NN/256), bucket = dst >> 8
#define CAP 8192            // padded bucket capacity (mean 4092, +64 sigma)
#define PMAX (NBKT * CAP)
#define TILE 4096
#define EPT 16              // TILE / 256
#define NTILE ((NE + TILE - 1) / TILE)   // 391

typedef __attribute__((ext_vector_type(8))) short bf16x8;
typedef __attribute__((ext_vector_type(4))) float f32x4;
typedef __attribute__((ext_vector_type(2))) unsigned int u32x2;
typedef __attribute__((ext_vector_type(4))) unsigned int u32x4;

__device__ __forceinline__ uint32_t rne_bf16(float v) {
    uint32_t u = __float_as_uint(v);
    return (u + 0x7fffu + ((u >> 16) & 1u)) >> 16;
}

// ---------------- CSR build ----------------

// tile-local LDS counting sort + coalesced segment write-out
__global__ __launch_bounds__(256) void k_bpart(const int* __restrict__ src,
                                               const int* __restrict__ dst,
                                               const float* __restrict__ w,
                                               int* __restrict__ bcur,
                                               int2* __restrict__ bpairs) {
    __shared__ int  hcnt[NBKT];      // count, then cursor
    __shared__ int  hoff[NBKT];      // local exclusive offset
    __shared__ int  hadj[NBKT];      // global base - local offset
    __shared__ int  sc0[512];
    __shared__ int  sc1[512];
    __shared__ int2 sT[TILE];        // 32 KB staged tile (bucket-sorted)
    __shared__ int  sAdj[TILE];      // 16 KB per-slot global adjust
    int tile0 = blockIdx.x * TILE;
    int t = threadIdx.x;
    for (int i = t; i < NBKT; i += 256) hcnt[i] = 0;
    __syncthreads();

    int   pk[EPT];
    int   bk[EPT];
    float wv[EPT];
    #pragma unroll
    for (int k = 0; k < EPT; k++) {
        int e = tile0 + t + k * 256;
        if (e < NE) {
            int d = dst[e];
            int b = d >> 8;
            pk[k] = (src[e] << 8) | (d & 255);
            wv[k] = w[e];
            bk[k] = b;
            atomicAdd(&hcnt[b], 1);
        } else {
            bk[k] = -1;
        }
    }
    __syncthreads();

    // inclusive scan of hcnt over 512 (padded) with ping-pong buffers
    sc0[t]       = (t < NBKT) ? hcnt[t] : 0;
    sc0[t + 256] = (t + 256 < NBKT) ? hcnt[t + 256] : 0;
    __syncthreads();
    int* cur = sc0;
    int* oth = sc1;
    for (int off = 1; off < 512; off <<= 1) {
        int v0 = cur[t]       + ((t       >= off) ? cur[t - off]       : 0);
        int v1 = cur[t + 256] + ((t + 256 >= off) ? cur[t + 256 - off] : 0);
        oth[t] = v0;
        oth[t + 256] = v1;
        __syncthreads();
        int* tmp = cur; cur = oth; oth = tmp;
    }
    for (int i = t; i < NBKT; i += 256) {
        int c = hcnt[i];
        int excl = cur[i] - c;
        hoff[i] = excl;
        int gbase = c ? atomicAdd(&bcur[i], c) : 0;
        hadj[i] = gbase - excl;
        hcnt[i] = 0;                 // reuse as local cursor
    }
    __syncthreads();

    // scatter into LDS (bucket-sorted order)
    #pragma unroll
    for (int k = 0; k < EPT; k++) {
        if (bk[k] >= 0) {
            int b = bk[k];
            int pos = hoff[b] + atomicAdd(&hcnt[b], 1);
            sT[pos] = make_int2(pk[k], __float_as_int(wv[k]));
            sAdj[pos] = hadj[b];
        }
    }
    __syncthreads();

    // linear write-out: consecutive slots in a bucket run -> consecutive
    // global addresses (coalesced bursts)
    int n = NE - tile0; if (n > TILE) n = TILE;
    for (int j = t; j < n; j += 256)
        bpairs[sAdj[j] + j] = sT[j];
}

// one block per bucket: stage bucket in LDS, then LDS counting sort.
__global__ __launch_bounds__(256) void k_bcsr(const int* __restrict__ bcur,
                                              const int2* __restrict__ bpairs,
                                              int* __restrict__ offs,
                                              int* __restrict__ ends,
                                              uint32_t* __restrict__ pairs) {
    __shared__ int2 sE[CAP];        // 64 KB bucket stage
    __shared__ int cnt[256];
    __shared__ int scn[256];
    __shared__ int cur[256];
    int k = blockIdx.x, t = threadIdx.x;
    int base = k * CAP;
    int scnt = bcur[k] - base;
    cnt[t] = 0;
    __syncthreads();
    for (int j = t; j < scnt; j += 256) {
        int2 q = bpairs[base + j];
        sE[j] = q;
        atomicAdd(&cnt[q.x & 255], 1);
    }
    __syncthreads();
    int v = cnt[t], acc = v;
    scn[t] = v;
    __syncthreads();
    for (int off = 1; off < 256; off <<= 1) {
        int u = (t >= off) ? scn[t - off] : 0;
        __syncthreads();
        acc += u;
        scn[t] = acc;
        __syncthreads();
    }
    int excl = acc - v;
    cur[t] = excl;
    int d = (k << 8) + t;
    if (d < NN) {
        offs[d] = base + excl;
        ends[d] = base + excl + v;
    }
    __syncthreads();
    for (int j = t; j < scnt; j += 256) {
        int2 q = sE[j];
        int pos = base + atomicAdd(&cur[q.x & 255], 1);
        uint32_t wb = rne_bf16(__int_as_float(q.y)) & 0x7fffu;   // w >= 0
        pairs[pos] = (wb << 17) | (uint32_t)(q.x >> 8);
    }
}

// ---------------- weight hi/lo split (+ bucket cursor init) ----------------

__global__ __launch_bounds__(256) void k_wsplit(const float* __restrict__ Wrel_mid,
                                                const float* __restrict__ Wroot_mid,
                                                uint16_t* __restrict__ WgH,
                                                uint16_t* __restrict__ WgL,
                                                uint16_t* __restrict__ WrH,
                                                uint16_t* __restrict__ WrL,
                                                int* __restrict__ bcur) {
    int i = blockIdx.x * blockDim.x + threadIdx.x;
    if (i < NBKT) bcur[i] = i * CAP;
    if (i >= 3 * 4096) return;
    float a = Wrel_mid[i];
    uint32_t ah = rne_bf16(a);
    float al = a - __uint_as_float(ah << 16);
    WgH[i] = (uint16_t)ah;
    WgL[i] = (uint16_t)rne_bf16(al);
    float b = Wroot_mid[i];
    uint32_t bh = rne_bf16(b);
    float bl = b - __uint_as_float(bh << 16);
    WrH[i] = (uint16_t)bh;
    WrL[i] = (uint16_t)rne_bf16(bl);
}

// ---------------- block-level epilogue helpers (k_l0pre only) --------------

__device__ __forceinline__ void mfma_epilogue(
        int lane, int w, const uint32_t* sH,
        const uint16_t* __restrict__ WgH, const uint16_t* __restrict__ WgL,
        const uint16_t* __restrict__ WrH, const uint16_t* __restrict__ WrL,
        const float* __restrict__ brel,
        uint16_t* sG, uint16_t* sR) {
    int row = lane & 15;
    int quad = lane >> 4;
    int kb = quad * 8;
    bf16x8 ah0 = *(const bf16x8*)&sH[row * 36 + quad * 4];
    bf16x8 ah1 = *(const bf16x8*)&sH[row * 36 + 16 + quad * 4];
    int oc = w * 16 + row;
    {
        bf16x8 bh0 = *(const bf16x8*)&WgH[oc * 64 + kb];
        bf16x8 bh1 = *(const bf16x8*)&WgH[oc * 64 + 32 + kb];
        bf16x8 bl0 = *(const bf16x8*)&WgL[oc * 64 + kb];
        bf16x8 bl1 = *(const bf16x8*)&WgL[oc * 64 + 32 + kb];
        f32x4 acc = {0.f, 0.f, 0.f, 0.f};
        acc = __builtin_amdgcn_mfma_f32_16x16x32_bf16(ah0, bh0, acc, 0, 0, 0);
        acc = __builtin_amdgcn_mfma_f32_16x16x32_bf16(ah1, bh1, acc, 0, 0, 0);
        acc = __builtin_amdgcn_mfma_f32_16x16x32_bf16(ah0, bl0, acc, 0, 0, 0);
        acc = __builtin_amdgcn_mfma_f32_16x16x32_bf16(ah1, bl1, acc, 0, 0, 0);
        #pragma unroll
        for (int r = 0; r < 4; r++)
            sG[(quad * 4 + r) * 68 + oc] = (uint16_t)rne_bf16(acc[r]);
    }
    {
        bf16x8 bh0 = *(const bf16x8*)&WrH[oc * 64 + kb];
        bf16x8 bh1 = *(const bf16x8*)&WrH[oc * 64 + 32 + kb];
        bf16x8 bl0 = *(const bf16x8*)&WrL[oc * 64 + kb];
        bf16x8 bl1 = *(const bf16x8*)&WrL[oc * 64 + 32 + kb];
        float bias = brel[oc];
        f32x4 acc = {bias, bias, bias, bias};
        acc = __builtin_amdgcn_mfma_f32_16x16x32_bf16(ah0, bh0, acc, 0, 0, 0);
        acc = __builtin_amdgcn_mfma_f32_16x16x32_bf16(ah1, bh1, acc, 0, 0, 0);
        acc = __builtin_amdgcn_mfma_f32_16x16x32_bf16(ah0, bl0, acc, 0, 0, 0);
        acc = __builtin_amdgcn_mfma_f32_16x16x32_bf16(ah1, bl1, acc, 0, 0, 0);
        #pragma unroll
        for (int r = 0; r < 4; r++)
            sR[(quad * 4 + r) * 68 + oc] = (uint16_t)rne_bf16(acc[r]);
    }
}

__device__ __forceinline__ void epilogue_writeout(
        int tid, int blk16, const uint16_t* sG, const uint16_t* sR,
        uint16_t* __restrict__ Gout, uint16_t* __restrict__ Rout) {
    const uint32_t* sGd = (const uint32_t*)sG;   // stride 34 dwords/node
    const uint32_t* sRd = (const uint32_t*)sR;
    uint32_t* Gd = (uint32_t*)Gout;
    uint32_t* Rd = (uint32_t*)Rout;
    #pragma unroll
    for (int it = 0; it < 2; it++) {
        int idx = it * 256 + tid;
        int nd = idx >> 5, col = idx & 31;
        Gd[(blk16 + nd) * 32 + col] = sGd[nd * 34 + col];
        Rd[(blk16 + nd) * 32 + col] = sRd[nd * 34 + col];
    }
}

// ---------------- layers ----------------

// layer 0 (fused): edge-parallel aggregation (all waves, shfl reduce), then
// h0 = relu(...) staged in LDS, MFMA epilogue -> G1,R1.
__global__ __launch_bounds__(256) void k_l0pre(
        const int* __restrict__ offs, const int* __restrict__ ends,
        const uint32_t* __restrict__ pairs, const float* __restrict__ x,
        const float* __restrict__ Wrel0, const float* __restrict__ brel0,
        const float* __restrict__ Wroot0,
        const uint16_t* __restrict__ WgH, const uint16_t* __restrict__ WgL,
        const uint16_t* __restrict__ WrH, const uint16_t* __restrict__ WrL,
        const float* __restrict__ brel,
        uint16_t* __restrict__ Gout, uint16_t* __restrict__ Rout) {
    __shared__ uint32_t sH[16 * 36];
    __shared__ uint16_t sG[16 * 68];
    __shared__ uint16_t sR[16 * 68];
    int c = threadIdx.x & 63;
    int w = threadIdx.x >> 6;
    int blk16 = blockIdx.x * 16;
    float agg[4];
    #pragma unroll
    for (int t = 0; t < 4; t++) {
        int node = blk16 + w * 4 + t;
        int b = offs[node], e = ends[node];
        float pp = 0.f;
        for (int j = b + c; j < e; j += 64) {
            uint32_t r = pairs[j];
            pp += __uint_as_float((r >> 17) << 16) * x[r & 0x1ffffu];
        }
        for (int o = 32; o > 0; o >>= 1) pp += __shfl_down(pp, o, 64);
        agg[t] = __shfl(pp, 0, 64);
    }
    float wr = Wrel0[c], br = brel0[c], wo = Wroot0[c];
    #pragma unroll
    for (int t = 0; t < 4; t++) {
        int node = blk16 + w * 4 + t;
        float v = agg[t] * wr + br + x[node] * wo;
        v = v > 0.f ? v : 0.f;
        uint32_t hb = rne_bf16(v);
        uint32_t pn = (uint32_t)__shfl_xor((int)hb, 1, 64);
        if (!(c & 1)) sH[(w * 4 + t) * 36 + (c >> 1)] = hb | (pn << 16);
    }
    __syncthreads();
    mfma_epilogue(c, w, sH, WgH, WgL, WrH, WrL, brel, sG, sR);
    __syncthreads();
    epilogue_writeout((int)threadIdx.x, blk16, sG, sR, Gout, Rout);
}

// transpose-read, byte-addressed: column = addr bits[6:3], subtile = the
// 128B-aligned base; lane reads bytes (addr&~127) + ((addr>>3)&15)*2 + 32*j
#define TRRA(dst, off) \
    asm volatile("ds_read_b64_tr_b16 %0, %1 offset:" #off \
                 : "=v"(dst) : "v"(trbA))
#define TRRB(dst, off) \
    asm volatile("ds_read_b64_tr_b16 %0, %1 offset:" #off \
                 : "=v"(dst) : "v"(trbB))

// Fused aggregation + pre-transform: 16 nodes per WAVE (64/block), MFMA
// consume with all 16 C rows live, wave-private epilogue, no block syncs.
template <bool LAST>
__global__ __launch_bounds__(256, 5) void k_aggfused(
        const int* __restrict__ offs, const int* __restrict__ ends,
        const uint32_t* __restrict__ pairs,
        const uint16_t* __restrict__ Gb, const uint16_t* __restrict__ Rb,
        const uint16_t* __restrict__ WgH, const uint16_t* __restrict__ WgL,
        const uint16_t* __restrict__ WrH, const uint16_t* __restrict__ WrL,
        const float* __restrict__ brel,
        uint16_t* __restrict__ Gout, uint16_t* __restrict__ Rout,
        const float* __restrict__ WrelL, const float* __restrict__ WrootL,
        float* __restrict__ sarr, float* __restrict__ rarr) {
    // 4 waves x 8KB: gather stage (2x4KB chunk bufs), then overlaid by
    // per-wave sH(2304B)+sG(2176B)+sR(2176B) in the epilogue. 32KB total
    // -> 5 blocks/CU.
    __shared__ __align__(128) char smem[32768];
    int c = threadIdx.x & 63;
    int w = threadIdx.x >> 6;
    int n0 = blockIdx.x * 64 + w * 16;    // wave owns nodes [n0, n0+16)

    // per-lane node bounds (lane's node = n0 + (c & 15); clamped at NN)
    int myNode = n0 + (c & 15);
    int nodeOK = myNode < NN;
    int nclamp = nodeOK ? myNode : NN - 1;
    int blo = offs[nclamp];
    int bhi = nodeOK ? ends[nclamp] : blo;
    uint32_t wid = (uint32_t)(bhi - blo);
    int start  = __builtin_amdgcn_readlane(blo, 0);
    int finish = __builtin_amdgcn_readlane(bhi, 15);

    int kq = (c >> 4) * 8;                // MFMA k-base for this quad
    // staging permutation (unchanged from r23/r26)
    int eprm  = ((c >> 5) << 2) | ((c >> 1) & 3);
    int lbyte = ((c >> 3) & 3) * 32 + (c & 1) * 16;
    char* stg = smem + w * 8192;          // chunk A: stg, chunk B: +4096
    uint32_t stgOff = (uint32_t)(uintptr_t)
        (__attribute__((address_space(3))) char*)stg;
    uint32_t trbA = stgOff + ((uint32_t)(c >> 4) << 10)
                          + ((uint32_t)(c & 15) << 3);
    uint32_t trbB = trbA + 4096;

    // C-init: direct Rb loads. acc16[nb][t] = C[node (c>>4)*4+t][nb*16+(c&15)]
    f32x4 acc16[4];
    #pragma unroll
    for (int nb = 0; nb < 4; nb++) {
        #pragma unroll
        for (int t = 0; t < 4; t++) {
            int node = n0 + (c >> 4) * 4 + t;
            int ncl = node < NN ? node : NN - 1;
            uint32_t rv = (uint32_t)Rb[ncl * 64 + nb * 16 + (c & 15)];
            acc16[nb][t] = __uint_as_float(rv << 16);
        }
    }

    const char* gbase = (const char*)Gb;
    // prologue pairs load (unconditional, clamped; lanes past end masked 0)
    int j0 = start + c; if (j0 > PMAX - 1) j0 = PMAX - 1;
    uint32_t praw = pairs[j0];
    uint32_t p = (start + c < finish) ? praw : 0;

    for (int cb = start; cb < finish; cb += 64) {
        // next super-chunk pairs (unconditional, clamped -> constant vmcnt)
        int jn = cb + 64 + c; if (jn > PMAX - 1) jn = PMAX - 1;
        uint32_t pr2 = pairs[jn];                               // vmem 1
        // ISSUE chunk A glds (edges 0-31)                       vmem 2-5
        #pragma unroll
        for (int i = 0; i < 4; i++) {
            uint32_t r = (uint32_t)__builtin_amdgcn_ds_bpermute(
                (eprm + i * 8) * 4, (int)p);
            uint32_t voff = ((r & 0x1ffffu) << 7) + (uint32_t)lbyte;
            __builtin_amdgcn_global_load_lds(
                (const __attribute__((address_space(1))) void*)(gbase + voff),
                (__attribute__((address_space(3))) void*)(stg + i * 1024),
                16, 0, 0);
        }
        // ISSUE chunk B glds (edges 32-63)                      vmem 6-9
        #pragma unroll
        for (int i = 0; i < 4; i++) {
            uint32_t r = (uint32_t)__builtin_amdgcn_ds_bpermute(
                (32 + eprm + i * 8) * 4, (int)p);
            uint32_t voff = ((r & 0x1ffffu) << 7) + (uint32_t)lbyte;
            __builtin_amdgcn_global_load_lds(
                (const __attribute__((address_space(1))) void*)(gbase + voff),
                (__attribute__((address_space(3))) void*)(stg + 4096 + i * 1024),
                16, 0, 0);
        }
        // A fragments for BOTH chunks, under the load shadow.
        // lane row = c&15 (node), k = kq+q; mask by per-lane segment bounds.
        uint32_t mA[8], mB[8];
        int dbA = cb + kq - blo;
        int dbB = cb + 32 + kq - blo;
        #pragma unroll
        for (int q = 0; q < 8; q++) {
            uint32_t rq = (uint32_t)__builtin_amdgcn_ds_bpermute(
                (kq + q) * 4, (int)p);
            mA[q] = ((uint32_t)(dbA + q) < wid) ? (rq >> 17) : 0u;
        }
        #pragma unroll
        for (int q = 0; q < 8; q++) {
            uint32_t rq = (uint32_t)__builtin_amdgcn_ds_bpermute(
                (32 + kq + q) * 4, (int)p);
            mB[q] = ((uint32_t)(dbB + q) < wid) ? (rq >> 17) : 0u;
        }
        u32x4 aav = { mA[0] | (mA[1] << 16), mA[2] | (mA[3] << 16),
                      mA[4] | (mA[5] << 16), mA[6] | (mA[7] << 16) };
        u32x4 abv = { mB[0] | (mB[1] << 16), mB[2] | (mB[3] << 16),
                      mB[4] | (mB[5] << 16), mB[6] | (mB[7] << 16) };
        bf16x8 afA = __builtin_bit_cast(bf16x8, aav);
        bf16x8 afB = __builtin_bit_cast(bf16x8, abv);
        // wait: pr2 + chunk A complete; chunk B (4) still in flight
        asm volatile("s_waitcnt vmcnt(4)" ::: "memory");
        {
            u32x2 tb0, tb1, tb2, tb3, tb4, tb5, tb6, tb7;
            TRRA(tb0, 0);   TRRA(tb1, 512);
            TRRA(tb2, 128); TRRA(tb3, 640);
            TRRA(tb4, 256); TRRA(tb5, 768);
            TRRA(tb6, 384); TRRA(tb7, 896);
            asm volatile("s_waitcnt lgkmcnt(0)" ::: "memory");
            __builtin_amdgcn_sched_barrier(0);
            u32x4 bb0 = { tb0.x, tb0.y, tb1.x, tb1.y };
            acc16[0] = __builtin_amdgcn_mfma_f32_16x16x32_bf16(
                afA, __builtin_bit_cast(bf16x8, bb0), acc16[0], 0, 0, 0);
            u32x4 bb1 = { tb2.x, tb2.y, tb3.x, tb3.y };
            acc16[1] = __builtin_amdgcn_mfma_f32_16x16x32_bf16(
                afA, __builtin_bit_cast(bf16x8, bb1), acc16[1], 0, 0, 0);
            u32x4 bb2 = { tb4.x, tb4.y, tb5.x, tb5.y };
            acc16[2] = __builtin_amdgcn_mfma_f32_16x16x32_bf16(
                afA, __builtin_bit_cast(bf16x8, bb2), acc16[2], 0, 0, 0);
            u32x4 bb3 = { tb6.x, tb6.y, tb7.x, tb7.y };
            acc16[3] = __builtin_amdgcn_mfma_f32_16x16x32_bf16(
                afA, __builtin_bit_cast(bf16x8, bb3), acc16[3], 0, 0, 0);
        }
        // wait: chunk B complete
        asm volatile("s_waitcnt vmcnt(0)" ::: "memory");
        {
            u32x2 tb0, tb1, tb2, tb3, tb4, tb5, tb6, tb7;
            TRRB(tb0, 0);   TRRB(tb1, 512);
            TRRB(tb2, 128); TRRB(tb3, 640);
            TRRB(tb4, 256); TRRB(tb5, 768);
            TRRB(tb6, 384); TRRB(tb7, 896);
            asm volatile("s_waitcnt lgkmcnt(0)" ::: "memory");
            __builtin_amdgcn_sched_barrier(0);
            u32x4 bb0 = { tb0.x, tb0.y, tb1.x, tb1.y };
            acc16[0] = __builtin_amdgcn_mfma_f32_16x16x32_bf16(
                afB, __builtin_bit_cast(bf16x8, bb0), acc16[0], 0, 0, 0);
            u32x4 bb1 = { tb2.x, tb2.y, tb3.x, tb3.y };
            acc16[1] = __builtin_amdgcn_mfma_f32_16x16x32_bf16(
                afB, __builtin_bit_cast(bf16x8, bb1), acc16[1], 0, 0, 0);
            u32x4 bb2 = { tb4.x, tb4.y, tb5.x, tb5.y };
            acc16[2] = __builtin_amdgcn_mfma_f32_16x16x32_bf16(
                afB, __builtin_bit_cast(bf16x8, bb2), acc16[2], 0, 0, 0);
            u32x4 bb3 = { tb6.x, tb6.y, tb7.x, tb7.y };
            acc16[3] = __builtin_amdgcn_mfma_f32_16x16x32_bf16(
                afB, __builtin_bit_cast(bf16x8, bb3), acc16[3], 0, 0, 0);
        }
        p = (cb + 64 + c < finish) ? pr2 : 0;
    }

    if (!LAST) {
        // pack relu(C) -> per-wave sH (overlay dead gather stage)
        uint32_t* sHw = (uint32_t*)(smem + w * 8192);
        #pragma unroll
        for (int t = 0; t < 4; t++) {
            #pragma unroll
            for (int nb = 0; nb < 4; nb++) {
                float v = acc16[nb][t];
                v = v > 0.f ? v : 0.f;
                uint32_t hb = rne_bf16(v);
                uint32_t pn2 = (uint32_t)__shfl_xor((int)hb, 1, 64);
                if (!(c & 1))
                    sHw[((c >> 4) * 4 + t) * 36 + nb * 8 + ((c & 15) >> 1)]
                        = hb | (pn2 << 16);
            }
        }
        asm volatile("s_waitcnt lgkmcnt(0)" ::: "memory");
        __builtin_amdgcn_sched_barrier(0);
        // wave-private epilogue: G = h x Wrel (hi/lo), R = h x Wroot + brel
        uint16_t* sGw = (uint16_t*)(smem + w * 8192 + 2304);
        uint16_t* sRw = (uint16_t*)(smem + w * 8192 + 2304 + 2176);
        int row = c & 15;
        int quad = c >> 4;
        int kb = quad * 8;
        bf16x8 ah0 = *(const bf16x8*)&sHw[row * 36 + quad * 4];
        bf16x8 ah1 = *(const bf16x8*)&sHw[row * 36 + 16 + quad * 4];
        #pragma unroll
        for (int ob = 0; ob < 4; ob++) {
            int oc = ob * 16 + row;
            {
                bf16x8 bh0 = *(const bf16x8*)&WgH[oc * 64 + kb];
                bf16x8 bh1 = *(const bf16x8*)&WgH[oc * 64 + 32 + kb];
                bf16x8 bl0 = *(const bf16x8*)&WgL[oc * 64 + kb];
                bf16x8 bl1 = *(const bf16x8*)&WgL[oc * 64 + 32 + kb];
                f32x4 acc = {0.f, 0.f, 0.f, 0.f};
                acc = __builtin_amdgcn_mfma_f32_16x16x32_bf16(ah0, bh0, acc, 0, 0, 0);
                acc = __builtin_amdgcn_mfma_f32_16x16x32_bf16(ah1, bh1, acc, 0, 0, 0);
                acc = __builtin_amdgcn_mfma_f32_16x16x32_bf16(ah0, bl0, acc, 0, 0, 0);
                acc = __builtin_amdgcn_mfma_f32_16x16x32_bf16(ah1, bl1, acc, 0, 0, 0);
                #pragma unroll
                for (int r = 0; r < 4; r++)
                    sGw[(quad * 4 + r) * 68 + oc] = (uint16_t)rne_bf16(acc[r]);
            }
            {
                bf16x8 bh0 = *(const bf16x8*)&WrH[oc * 64 + kb];
                bf16x8 bh1 = *(const bf16x8*)&WrH[oc * 64 + 32 + kb];
                bf16x8 bl0 = *(const bf16x8*)&WrL[oc * 64 + kb];
                bf16x8 bl1 = *(const bf16x8*)&WrL[oc * 64 + 32 + kb];
                float bias = brel[oc];
                f32x4 acc = {bias, bias, bias, bias};
                acc = __builtin_amdgcn_mfma_f32_16x16x32_bf16(ah0, bh0, acc, 0, 0, 0);
                acc = __builtin_amdgcn_mfma_f32_16x16x32_bf16(ah1, bh1, acc, 0, 0, 0);
                acc = __builtin_amdgcn_mfma_f32_16x16x32_bf16(ah0, bl0, acc, 0, 0, 0);
                acc = __builtin_amdgcn_mfma_f32_16x16x32_bf16(ah1, bl1, acc, 0, 0, 0);
                #pragma unroll
                for (int r = 0; r < 4; r++)
                    sRw[(quad * 4 + r) * 68 + oc] = (uint16_t)rne_bf16(acc[r]);
            }
        }
        asm volatile("s_waitcnt lgkmcnt(0)" ::: "memory");
        __builtin_amdgcn_sched_barrier(0);
        // per-wave write-out: 16 nodes x 32 dwords, 64 lanes -> 8 iters
        const uint32_t* sGd = (const uint32_t*)sGw;
        const uint32_t* sRd = (const uint32_t*)sRw;
        uint32_t* Gd = (uint32_t*)Gout;
        uint32_t* Rd = (uint32_t*)Rout;
        #pragma unroll
        for (int it = 0; it < 8; it++) {
            int idx = it * 64 + c;
            int nd = idx >> 5, col = idx & 31;
            int node = n0 + nd;
            if (node < NN) {
                Gd[node * 32 + col] = sGd[nd * 34 + col];
                Rd[node * 32 + col] = sRd[nd * 34 + col];
            }
        }
    } else {
        float wl[4], wo[4];
        #pragma unroll
        for (int nb = 0; nb < 4; nb++) {
            wl[nb] = WrelL[nb * 16 + (c & 15)];
            wo[nb] = WrootL[nb * 16 + (c & 15)];
        }
        #pragma unroll
        for (int t = 0; t < 4; t++) {
            float pa = 0.f, pr = 0.f;
            #pragma unroll
            for (int nb = 0; nb < 4; nb++) {
                float v = acc16[nb][t];
                v = v > 0.f ? v : 0.f;
                pa += v * wl[nb];
                pr += v * wo[nb];
            }
            #pragma unroll
            for (int o = 8; o > 0; o >>= 1) {
                pa += __shfl_down(pa, o, 64);
                pr += __shfl_down(pr, o, 64);
            }
            int node = n0 + (c >> 4) * 4 + t;
            if (!(c & 15) && node < NN) { sarr[node] = pa; rarr[node] = pr; }
        }
    }
}

// final edge pass: wave-per-4-nodes edge-parallel gather + shfl reduce
__global__ __launch_bounds__(256) void k_last(
        const int* __restrict__ offs, const int* __restrict__ ends,
        const uint32_t* __restrict__ pairs,
        const float* __restrict__ sarr, const float* __restrict__ rarr,
        const float* __restrict__ brelL, float* __restrict__ out) {
    int c = threadIdx.x & 63;
    int w = threadIdx.x >> 6;
    int blk16 = blockIdx.x * 16;
    float b0 = brelL[0];
    #pragma unroll
    for (int t = 0; t < 4; t++) {
        int node = blk16 + w * 4 + t;
        int b = offs[node], e = ends[node];
        float pp = 0.f;
        for (int j = b + c; j < e; j += 64) {
            uint32_t r = pairs[j];
            pp += __uint_as_float((r >> 17) << 16) * sarr[r & 0x1ffffu];
        }
        #pragma unroll
        for (int o = 32; o > 0; o >>= 1) pp += __shfl_down(pp, o, 64);
        if (c == 0) out[node] = pp + rarr[node] + b0;
    }
}

extern "C" void kernel_launch(void* const* d_in, const int* in_sizes, int n_in,
                              void* d_out, int out_size, void* d_ws, size_t ws_size,
                              hipStream_t stream) {
    const float* x        = (const float*)d_in[0];
    const int*   ei       = (const int*)d_in[1];
    const float* ew       = (const float*)d_in[2];
    const float* Wrel0    = (const float*)d_in[3];
    const float* brel0    = (const float*)d_in[4];
    const float* Wroot0   = (const float*)d_in[5];
    const float* Wrel_mid = (const float*)d_in[6];
    const float* brel_mid = (const float*)d_in[7];
    const float* Wroot_mid= (const float*)d_in[8];
    const float* WrelL    = (const float*)d_in[9];
    const float* brelL    = (const float*)d_in[10];
    const float* WrootL   = (const float*)d_in[11];
    float* out = (float*)d_out;

    const int* src  = ei;
    const int* dstp = ei + NE;

    char* w = (char*)d_ws;
    size_t o = 0;
    auto alloc = [&](size_t b) -> void* {
        void* r = (void*)(w + o);
        o += (b + 255) & ~(size_t)255;
        return r;
    };
    int*      offs  = (int*)alloc((size_t)NN * 4);
    int*      ends  = (int*)alloc((size_t)NN * 4);
    int*      bcur  = (int*)alloc((size_t)NBKT * 4);
    uint16_t* WgH   = (uint16_t*)alloc((size_t)3 * 4096 * 2);
    uint16_t* WgL   = (uint16_t*)alloc((size_t)3 * 4096 * 2);
    uint16_t* WrH   = (uint16_t*)alloc((size_t)3 * 4096 * 2);
    uint16_t* WrL   = (uint16_t*)alloc((size_t)3 * 4096 * 2);
    float*    sarr  = (float*)alloc((size_t)NN * 4);
    float*    rarr  = (float*)alloc((size_t)NN * 4);
    uint32_t* pairs = (uint32_t*)alloc((size_t)NBKT * CAP * 4);  // 12.8 MB padded
    uint16_t* GbA   = (uint16_t*)alloc((size_t)NN * HID * 2);    // 12.8 MB
    uint16_t* RbA   = (uint16_t*)alloc((size_t)NN * HID * 2);
    uint16_t* GbB   = (uint16_t*)alloc((size_t)NN * HID * 2);    // GbB/RbB contiguous
    uint16_t* RbB   = (uint16_t*)alloc((size_t)NN * HID * 2);
    (void)RbB;
    // bpairs (NBKT*CAP*8B = 25.6MB) aliases GbB+RbB (contiguous; dead before
    // mid layer 1 writes set B)
    int2*  bpairs = (int2*)GbB;

    // weight split + bucket cursor init (one launch)
    k_wsplit<<<(3 * 4096 + 255) / 256, 256, 0, stream>>>(
        Wrel_mid, Wroot_mid, WgH, WgL, WrH, WrL, bcur);

    // CSR build (padded buckets)
    k_bpart<<<NTILE, 256, 0, stream>>>(src, dstp, ew, bcur, bpairs);
    k_bcsr<<<NBKT, 256, 0, stream>>>(bcur, bpairs, offs, ends, pairs);

    // layer 0 (agg + transform + pre) -> G1,R1 (set A)
    k_l0pre<<<NN / 16, 256, 0, stream>>>(
        offs, ends, pairs, x, Wrel0, brel0, Wroot0,
        WgH, WgL, WrH, WrL, brel_mid, GbA, RbA);

    int nagg = (NN + 63) / 64;   // 1563 blocks, 64 nodes/block
    // mid layer 1: consume set A, produce set B (weights index 1)
    k_aggfused<false><<<nagg, 256, 0, stream>>>(
        offs, ends, pairs, GbA, RbA,
        WgH + 4096, WgL + 4096, WrH + 4096, WrL + 4096, brel_mid + HID,
        GbB, RbB, WrelL, WrootL, sarr, rarr);
    // mid layer 2: consume set B, produce set A (weights index 2)
    k_aggfused<false><<<nagg, 256, 0, stream>>>(
        offs, ends, pairs, GbB, RbB,
        WgH + 2 * 4096, WgL + 2 * 4096, WrH + 2 * 4096, WrL + 2 * 4096,
        brel_mid + 2 * HID, GbA, RbA, WrelL, WrootL, sarr, rarr);
    // mid layer 3 (LAST): consume set A, produce s/r scalars
    k_aggfused<true><<<nagg, 256, 0, stream>>>(
        offs, ends, pairs, GbA, RbA,
        WgH, WgL, WrH, WrL, brel_mid,
        GbB, RbB, WrelL, WrootL, sarr, rarr);

    // final edge pass on scalars (16 nodes/block -> NN/16 blocks)
    k_last<<<NN / 16, 256, 0, stream>>>(offs, ends, pairs, sarr, rarr, brelL, out);
}

// Round 9
// 297.554 us; speedup vs baseline: 1.0902x; 1.0305x over previous
//
#include <hip/hip_runtime.h>
#include <stdint.h>

// GraphConv x5 on MI355X — round 28.
// vs round 27 (306.6us; k_aggfused 53.6us, VALUBusy 16%, Occupancy 28%):
// wall is gather latency x insufficient wave overlap — 1563 4-wave blocks
// = only 6.1 blocks/CU of work; ~2.25 resident waves/SIMD cover two ~1Kcy
// drains/iter. The kernel is already wave-private (no __syncthreads), so:
// 1-WAVE workgroups (64 thr, 16 nodes, 8KB LDS), grid 6250 -> 20 waves/CU
// residency (5/SIMD) and 4x finer load-balance granularity. No other change.

#define NN 100000
#define NE 1600000
#define HID 64
#define NBKT 391            // ceil(NN/256), bucket = dst >> 8
#define CAP 8192            // padded bucket capacity (mean 4092, +64 sigma)
#define PMAX (NBKT * CAP)
#define TILE 4096
#define EPT 16              // TILE / 256
#define NTILE ((NE + TILE - 1) / TILE)   // 391

typedef __attribute__((ext_vector_type(8))) short bf16x8;
typedef __attribute__((ext_vector_type(4))) float f32x4;
typedef __attribute__((ext_vector_type(2))) unsigned int u32x2;
typedef __attribute__((ext_vector_type(4))) unsigned int u32x4;

__device__ __forceinline__ uint32_t rne_bf16(float v) {
    uint32_t u = __float_as_uint(v);
    return (u + 0x7fffu + ((u >> 16) & 1u)) >> 16;
}

// ---------------- CSR build ----------------

// tile-local LDS counting sort + coalesced segment write-out
__global__ __launch_bounds__(256) void k_bpart(const int* __restrict__ src,
                                               const int* __restrict__ dst,
                                               const float* __restrict__ w,
                                               int* __restrict__ bcur,
                                               int2* __restrict__ bpairs) {
    __shared__ int  hcnt[NBKT];      // count, then cursor
    __shared__ int  hoff[NBKT];      // local exclusive offset
    __shared__ int  hadj[NBKT];      // global base - local offset
    __shared__ int  sc0[512];
    __shared__ int  sc1[512];
    __shared__ int2 sT[TILE];        // 32 KB staged tile (bucket-sorted)
    __shared__ int  sAdj[TILE];      // 16 KB per-slot global adjust
    int tile0 = blockIdx.x * TILE;
    int t = threadIdx.x;
    for (int i = t; i < NBKT; i += 256) hcnt[i] = 0;
    __syncthreads();

    int   pk[EPT];
    int   bk[EPT];
    float wv[EPT];
    #pragma unroll
    for (int k = 0; k < EPT; k++) {
        int e = tile0 + t + k * 256;
        if (e < NE) {
            int d = dst[e];
            int b = d >> 8;
            pk[k] = (src[e] << 8) | (d & 255);
            wv[k] = w[e];
            bk[k] = b;
            atomicAdd(&hcnt[b], 1);
        } else {
            bk[k] = -1;
        }
    }
    __syncthreads();

    // inclusive scan of hcnt over 512 (padded) with ping-pong buffers
    sc0[t]       = (t < NBKT) ? hcnt[t] : 0;
    sc0[t + 256] = (t + 256 < NBKT) ? hcnt[t + 256] : 0;
    __syncthreads();
    int* cur = sc0;
    int* oth = sc1;
    for (int off = 1; off < 512; off <<= 1) {
        int v0 = cur[t]       + ((t       >= off) ? cur[t - off]       : 0);
        int v1 = cur[t + 256] + ((t + 256 >= off) ? cur[t + 256 - off] : 0);
        oth[t] = v0;
        oth[t + 256] = v1;
        __syncthreads();
        int* tmp = cur; cur = oth; oth = tmp;
    }
    for (int i = t; i < NBKT; i += 256) {
        int c = hcnt[i];
        int excl = cur[i] - c;
        hoff[i] = excl;
        int gbase = c ? atomicAdd(&bcur[i], c) : 0;
        hadj[i] = gbase - excl;
        hcnt[i] = 0;                 // reuse as local cursor
    }
    __syncthreads();

    // scatter into LDS (bucket-sorted order)
    #pragma unroll
    for (int k = 0; k < EPT; k++) {
        if (bk[k] >= 0) {
            int b = bk[k];
            int pos = hoff[b] + atomicAdd(&hcnt[b], 1);
            sT[pos] = make_int2(pk[k], __float_as_int(wv[k]));
            sAdj[pos] = hadj[b];
        }
    }
    __syncthreads();

    // linear write-out: consecutive slots in a bucket run -> consecutive
    // global addresses (coalesced bursts)
    int n = NE - tile0; if (n > TILE) n = TILE;
    for (int j = t; j < n; j += 256)
        bpairs[sAdj[j] + j] = sT[j];
}

// one block per bucket: stage bucket in LDS, then LDS counting sort.
__global__ __launch_bounds__(256) void k_bcsr(const int* __restrict__ bcur,
                                              const int2* __restrict__ bpairs,
                                              int* __restrict__ offs,
                                              int* __restrict__ ends,
                                              uint32_t* __restrict__ pairs) {
    __shared__ int2 sE[CAP];        // 64 KB bucket stage
    __shared__ int cnt[256];
    __shared__ int scn[256];
    __shared__ int cur[256];
    int k = blockIdx.x, t = threadIdx.x;
    int base = k * CAP;
    int scnt = bcur[k] - base;
    cnt[t] = 0;
    __syncthreads();
    for (int j = t; j < scnt; j += 256) {
        int2 q = bpairs[base + j];
        sE[j] = q;
        atomicAdd(&cnt[q.x & 255], 1);
    }
    __syncthreads();
    int v = cnt[t], acc = v;
    scn[t] = v;
    __syncthreads();
    for (int off = 1; off < 256; off <<= 1) {
        int u = (t >= off) ? scn[t - off] : 0;
        __syncthreads();
        acc += u;
        scn[t] = acc;
        __syncthreads();
    }
    int excl = acc - v;
    cur[t] = excl;
    int d = (k << 8) + t;
    if (d < NN) {
        offs[d] = base + excl;
        ends[d] = base + excl + v;
    }
    __syncthreads();
    for (int j = t; j < scnt; j += 256) {
        int2 q = sE[j];
        int pos = base + atomicAdd(&cur[q.x & 255], 1);
        uint32_t wb = rne_bf16(__int_as_float(q.y)) & 0x7fffu;   // w >= 0
        pairs[pos] = (wb << 17) | (uint32_t)(q.x >> 8);
    }
}

// ---------------- weight hi/lo split (+ bucket cursor init) ----------------

__global__ __launch_bounds__(256) void k_wsplit(const float* __restrict__ Wrel_mid,
                                                const float* __restrict__ Wroot_mid,
                                                uint16_t* __restrict__ WgH,
                                                uint16_t* __restrict__ WgL,
                                                uint16_t* __restrict__ WrH,
                                                uint16_t* __restrict__ WrL,
                                                int* __restrict__ bcur) {
    int i = blockIdx.x * blockDim.x + threadIdx.x;
    if (i < NBKT) bcur[i] = i * CAP;
    if (i >= 3 * 4096) return;
    float a = Wrel_mid[i];
    uint32_t ah = rne_bf16(a);
    float al = a - __uint_as_float(ah << 16);
    WgH[i] = (uint16_t)ah;
    WgL[i] = (uint16_t)rne_bf16(al);
    float b = Wroot_mid[i];
    uint32_t bh = rne_bf16(b);
    float bl = b - __uint_as_float(bh << 16);
    WrH[i] = (uint16_t)bh;
    WrL[i] = (uint16_t)rne_bf16(bl);
}

// ---------------- block-level epilogue helpers (k_l0pre only) --------------

__device__ __forceinline__ void mfma_epilogue(
        int lane, int w, const uint32_t* sH,
        const uint16_t* __restrict__ WgH, const uint16_t* __restrict__ WgL,
        const uint16_t* __restrict__ WrH, const uint16_t* __restrict__ WrL,
        const float* __restrict__ brel,
        uint16_t* sG, uint16_t* sR) {
    int row = lane & 15;
    int quad = lane >> 4;
    int kb = quad * 8;
    bf16x8 ah0 = *(const bf16x8*)&sH[row * 36 + quad * 4];
    bf16x8 ah1 = *(const bf16x8*)&sH[row * 36 + 16 + quad * 4];
    int oc = w * 16 + row;
    {
        bf16x8 bh0 = *(const bf16x8*)&WgH[oc * 64 + kb];
        bf16x8 bh1 = *(const bf16x8*)&WgH[oc * 64 + 32 + kb];
        bf16x8 bl0 = *(const bf16x8*)&WgL[oc * 64 + kb];
        bf16x8 bl1 = *(const bf16x8*)&WgL[oc * 64 + 32 + kb];
        f32x4 acc = {0.f, 0.f, 0.f, 0.f};
        acc = __builtin_amdgcn_mfma_f32_16x16x32_bf16(ah0, bh0, acc, 0, 0, 0);
        acc = __builtin_amdgcn_mfma_f32_16x16x32_bf16(ah1, bh1, acc, 0, 0, 0);
        acc = __builtin_amdgcn_mfma_f32_16x16x32_bf16(ah0, bl0, acc, 0, 0, 0);
        acc = __builtin_amdgcn_mfma_f32_16x16x32_bf16(ah1, bl1, acc, 0, 0, 0);
        #pragma unroll
        for (int r = 0; r < 4; r++)
            sG[(quad * 4 + r) * 68 + oc] = (uint16_t)rne_bf16(acc[r]);
    }
    {
        bf16x8 bh0 = *(const bf16x8*)&WrH[oc * 64 + kb];
        bf16x8 bh1 = *(const bf16x8*)&WrH[oc * 64 + 32 + kb];
        bf16x8 bl0 = *(const bf16x8*)&WrL[oc * 64 + kb];
        bf16x8 bl1 = *(const bf16x8*)&WrL[oc * 64 + 32 + kb];
        float bias = brel[oc];
        f32x4 acc = {bias, bias, bias, bias};
        acc = __builtin_amdgcn_mfma_f32_16x16x32_bf16(ah0, bh0, acc, 0, 0, 0);
        acc = __builtin_amdgcn_mfma_f32_16x16x32_bf16(ah1, bh1, acc, 0, 0, 0);
        acc = __builtin_amdgcn_mfma_f32_16x16x32_bf16(ah0, bl0, acc, 0, 0, 0);
        acc = __builtin_amdgcn_mfma_f32_16x16x32_bf16(ah1, bl1, acc, 0, 0, 0);
        #pragma unroll
        for (int r = 0; r < 4; r++)
            sR[(quad * 4 + r) * 68 + oc] = (uint16_t)rne_bf16(acc[r]);
    }
}

__device__ __forceinline__ void epilogue_writeout(
        int tid, int blk16, const uint16_t* sG, const uint16_t* sR,
        uint16_t* __restrict__ Gout, uint16_t* __restrict__ Rout) {
    const uint32_t* sGd = (const uint32_t*)sG;   // stride 34 dwords/node
    const uint32_t* sRd = (const uint32_t*)sR;
    uint32_t* Gd = (uint32_t*)Gout;
    uint32_t* Rd = (uint32_t*)Rout;
    #pragma unroll
    for (int it = 0; it < 2; it++) {
        int idx = it * 256 + tid;
        int nd = idx >> 5, col = idx & 31;
        Gd[(blk16 + nd) * 32 + col] = sGd[nd * 34 + col];
        Rd[(blk16 + nd) * 32 + col] = sRd[nd * 34 + col];
    }
}

// ---------------- layers ----------------

// layer 0 (fused): edge-parallel aggregation (all waves, shfl reduce), then
// h0 = relu(...) staged in LDS, MFMA epilogue -> G1,R1.
__global__ __launch_bounds__(256) void k_l0pre(
        const int* __restrict__ offs, const int* __restrict__ ends,
        const uint32_t* __restrict__ pairs, const float* __restrict__ x,
        const float* __restrict__ Wrel0, const float* __restrict__ brel0,
        const float* __restrict__ Wroot0,
        const uint16_t* __restrict__ WgH, const uint16_t* __restrict__ WgL,
        const uint16_t* __restrict__ WrH, const uint16_t* __restrict__ WrL,
        const float* __restrict__ brel,
        uint16_t* __restrict__ Gout, uint16_t* __restrict__ Rout) {
    __shared__ uint32_t sH[16 * 36];
    __shared__ uint16_t sG[16 * 68];
    __shared__ uint16_t sR[16 * 68];
    int c = threadIdx.x & 63;
    int w = threadIdx.x >> 6;
    int blk16 = blockIdx.x * 16;
    float agg[4];
    #pragma unroll
    for (int t = 0; t < 4; t++) {
        int node = blk16 + w * 4 + t;
        int b = offs[node], e = ends[node];
        float pp = 0.f;
        for (int j = b + c; j < e; j += 64) {
            uint32_t r = pairs[j];
            pp += __uint_as_float((r >> 17) << 16) * x[r & 0x1ffffu];
        }
        for (int o = 32; o > 0; o >>= 1) pp += __shfl_down(pp, o, 64);
        agg[t] = __shfl(pp, 0, 64);
    }
    float wr = Wrel0[c], br = brel0[c], wo = Wroot0[c];
    #pragma unroll
    for (int t = 0; t < 4; t++) {
        int node = blk16 + w * 4 + t;
        float v = agg[t] * wr + br + x[node] * wo;
        v = v > 0.f ? v : 0.f;
        uint32_t hb = rne_bf16(v);
        uint32_t pn = (uint32_t)__shfl_xor((int)hb, 1, 64);
        if (!(c & 1)) sH[(w * 4 + t) * 36 + (c >> 1)] = hb | (pn << 16);
    }
    __syncthreads();
    mfma_epilogue(c, w, sH, WgH, WgL, WrH, WrL, brel, sG, sR);
    __syncthreads();
    epilogue_writeout((int)threadIdx.x, blk16, sG, sR, Gout, Rout);
}

// transpose-read, byte-addressed: column = addr bits[6:3], subtile = the
// 128B-aligned base; lane reads bytes (addr&~127) + ((addr>>3)&15)*2 + 32*j
#define TRRA(dst, off) \
    asm volatile("ds_read_b64_tr_b16 %0, %1 offset:" #off \
                 : "=v"(dst) : "v"(trbA))
#define TRRB(dst, off) \
    asm volatile("ds_read_b64_tr_b16 %0, %1 offset:" #off \
                 : "=v"(dst) : "v"(trbB))

// Fused aggregation + pre-transform: 16 nodes per 1-WAVE workgroup (64 thr,
// 8KB LDS -> 20 waves/CU residency), MFMA consume with all 16 C rows live,
// wave-private epilogue, no block syncs.
template <bool LAST>
__global__ __launch_bounds__(64, 5) void k_aggfused(
        const int* __restrict__ offs, const int* __restrict__ ends,
        const uint32_t* __restrict__ pairs,
        const uint16_t* __restrict__ Gb, const uint16_t* __restrict__ Rb,
        const uint16_t* __restrict__ WgH, const uint16_t* __restrict__ WgL,
        const uint16_t* __restrict__ WrH, const uint16_t* __restrict__ WrL,
        const float* __restrict__ brel,
        uint16_t* __restrict__ Gout, uint16_t* __restrict__ Rout,
        const float* __restrict__ WrelL, const float* __restrict__ WrootL,
        float* __restrict__ sarr, float* __restrict__ rarr) {
    // 8KB: gather stage (2x4KB chunk bufs), overlaid by sH(2304B)+sG(2176B)
    // +sR(2176B) in the epilogue.
    __shared__ __align__(128) char smem[8192];
    int c = threadIdx.x;                  // 0..63
    int n0 = blockIdx.x * 16;             // wave owns nodes [n0, n0+16)

    // per-lane node bounds (lane's node = n0 + (c & 15); clamped at NN)
    int myNode = n0 + (c & 15);
    int nodeOK = myNode < NN;
    int nclamp = nodeOK ? myNode : NN - 1;
    int blo = offs[nclamp];
    int bhi = nodeOK ? ends[nclamp] : blo;
    uint32_t wid = (uint32_t)(bhi - blo);
    int start  = __builtin_amdgcn_readlane(blo, 0);
    int finish = __builtin_amdgcn_readlane(bhi, 15);

    int kq = (c >> 4) * 8;                // MFMA k-base for this quad
    // staging permutation (unchanged)
    int eprm  = ((c >> 5) << 2) | ((c >> 1) & 3);
    int lbyte = ((c >> 3) & 3) * 32 + (c & 1) * 16;
    char* stg = smem;                     // chunk A: stg, chunk B: +4096
    uint32_t stgOff = (uint32_t)(uintptr_t)
        (__attribute__((address_space(3))) char*)stg;
    uint32_t trbA = stgOff + ((uint32_t)(c >> 4) << 10)
                          + ((uint32_t)(c & 15) << 3);
    uint32_t trbB = trbA + 4096;

    // C-init: direct Rb loads. acc16[nb][t] = C[node (c>>4)*4+t][nb*16+(c&15)]
    f32x4 acc16[4];
    #pragma unroll
    for (int nb = 0; nb < 4; nb++) {
        #pragma unroll
        for (int t = 0; t < 4; t++) {
            int node = n0 + (c >> 4) * 4 + t;
            int ncl = node < NN ? node : NN - 1;
            uint32_t rv = (uint32_t)Rb[ncl * 64 + nb * 16 + (c & 15)];
            acc16[nb][t] = __uint_as_float(rv << 16);
        }
    }

    const char* gbase = (const char*)Gb;
    // prologue pairs load (unconditional, clamped; lanes past end masked 0)
    int j0 = start + c; if (j0 > PMAX - 1) j0 = PMAX - 1;
    uint32_t praw = pairs[j0];
    uint32_t p = (start + c < finish) ? praw : 0;

    for (int cb = start; cb < finish; cb += 64) {
        // next super-chunk pairs (unconditional, clamped -> constant vmcnt)
        int jn = cb + 64 + c; if (jn > PMAX - 1) jn = PMAX - 1;
        uint32_t pr2 = pairs[jn];                               // vmem 1
        // ISSUE chunk A glds (edges 0-31)                       vmem 2-5
        #pragma unroll
        for (int i = 0; i < 4; i++) {
            uint32_t r = (uint32_t)__builtin_amdgcn_ds_bpermute(
                (eprm + i * 8) * 4, (int)p);
            uint32_t voff = ((r & 0x1ffffu) << 7) + (uint32_t)lbyte;
            __builtin_amdgcn_global_load_lds(
                (const __attribute__((address_space(1))) void*)(gbase + voff),
                (__attribute__((address_space(3))) void*)(stg + i * 1024),
                16, 0, 0);
        }
        // ISSUE chunk B glds (edges 32-63)                      vmem 6-9
        #pragma unroll
        for (int i = 0; i < 4; i++) {
            uint32_t r = (uint32_t)__builtin_amdgcn_ds_bpermute(
                (32 + eprm + i * 8) * 4, (int)p);
            uint32_t voff = ((r & 0x1ffffu) << 7) + (uint32_t)lbyte;
            __builtin_amdgcn_global_load_lds(
                (const __attribute__((address_space(1))) void*)(gbase + voff),
                (__attribute__((address_space(3))) void*)(stg + 4096 + i * 1024),
                16, 0, 0);
        }
        // A fragments for BOTH chunks, under the load shadow.
        uint32_t mA[8], mB[8];
        int dbA = cb + kq - blo;
        int dbB = cb + 32 + kq - blo;
        #pragma unroll
        for (int q = 0; q < 8; q++) {
            uint32_t rq = (uint32_t)__builtin_amdgcn_ds_bpermute(
                (kq + q) * 4, (int)p);
            mA[q] = ((uint32_t)(dbA + q) < wid) ? (rq >> 17) : 0u;
        }
        #pragma unroll
        for (int q = 0; q < 8; q++) {
            uint32_t rq = (uint32_t)__builtin_amdgcn_ds_bpermute(
                (32 + kq + q) * 4, (int)p);
            mB[q] = ((uint32_t)(dbB + q) < wid) ? (rq >> 17) : 0u;
        }
        u32x4 aav = { mA[0] | (mA[1] << 16), mA[2] | (mA[3] << 16),
                      mA[4] | (mA[5] << 16), mA[6] | (mA[7] << 16) };
        u32x4 abv = { mB[0] | (mB[1] << 16), mB[2] | (mB[3] << 16),
                      mB[4] | (mB[5] << 16), mB[6] | (mB[7] << 16) };
        bf16x8 afA = __builtin_bit_cast(bf16x8, aav);
        bf16x8 afB = __builtin_bit_cast(bf16x8, abv);
        // wait: pr2 + chunk A complete; chunk B (4) still in flight
        asm volatile("s_waitcnt vmcnt(4)" ::: "memory");
        {
            u32x2 tb0, tb1, tb2, tb3, tb4, tb5, tb6, tb7;
            TRRA(tb0, 0);   TRRA(tb1, 512);
            TRRA(tb2, 128); TRRA(tb3, 640);
            TRRA(tb4, 256); TRRA(tb5, 768);
            TRRA(tb6, 384); TRRA(tb7, 896);
            asm volatile("s_waitcnt lgkmcnt(0)" ::: "memory");
            __builtin_amdgcn_sched_barrier(0);
            u32x4 bb0 = { tb0.x, tb0.y, tb1.x, tb1.y };
            acc16[0] = __builtin_amdgcn_mfma_f32_16x16x32_bf16(
                afA, __builtin_bit_cast(bf16x8, bb0), acc16[0], 0, 0, 0);
            u32x4 bb1 = { tb2.x, tb2.y, tb3.x, tb3.y };
            acc16[1] = __builtin_amdgcn_mfma_f32_16x16x32_bf16(
                afA, __builtin_bit_cast(bf16x8, bb1), acc16[1], 0, 0, 0);
            u32x4 bb2 = { tb4.x, tb4.y, tb5.x, tb5.y };
            acc16[2] = __builtin_amdgcn_mfma_f32_16x16x32_bf16(
                afA, __builtin_bit_cast(bf16x8, bb2), acc16[2], 0, 0, 0);
            u32x4 bb3 = { tb6.x, tb6.y, tb7.x, tb7.y };
            acc16[3] = __builtin_amdgcn_mfma_f32_16x16x32_bf16(
                afA, __builtin_bit_cast(bf16x8, bb3), acc16[3], 0, 0, 0);
        }
        // wait: chunk B complete
        asm volatile("s_waitcnt vmcnt(0)" ::: "memory");
        {
            u32x2 tb0, tb1, tb2, tb3, tb4, tb5, tb6, tb7;
            TRRB(tb0, 0);   TRRB(tb1, 512);
            TRRB(tb2, 128); TRRB(tb3, 640);
            TRRB(tb4, 256); TRRB(tb5, 768);
            TRRB(tb6, 384); TRRB(tb7, 896);
            asm volatile("s_waitcnt lgkmcnt(0)" ::: "memory");
            __builtin_amdgcn_sched_barrier(0);
            u32x4 bb0 = { tb0.x, tb0.y, tb1.x, tb1.y };
            acc16[0] = __builtin_amdgcn_mfma_f32_16x16x32_bf16(
                afB, __builtin_bit_cast(bf16x8, bb0), acc16[0], 0, 0, 0);
            u32x4 bb1 = { tb2.x, tb2.y, tb3.x, tb3.y };
            acc16[1] = __builtin_amdgcn_mfma_f32_16x16x32_bf16(
                afB, __builtin_bit_cast(bf16x8, bb1), acc16[1], 0, 0, 0);
            u32x4 bb2 = { tb4.x, tb4.y, tb5.x, tb5.y };
            acc16[2] = __builtin_amdgcn_mfma_f32_16x16x32_bf16(
                afB, __builtin_bit_cast(bf16x8, bb2), acc16[2], 0, 0, 0);
            u32x4 bb3 = { tb6.x, tb6.y, tb7.x, tb7.y };
            acc16[3] = __builtin_amdgcn_mfma_f32_16x16x32_bf16(
                afB, __builtin_bit_cast(bf16x8, bb3), acc16[3], 0, 0, 0);
        }
        p = (cb + 64 + c < finish) ? pr2 : 0;
    }

    if (!LAST) {
        // pack relu(C) -> sH (overlay dead gather stage)
        uint32_t* sHw = (uint32_t*)smem;
        #pragma unroll
        for (int t = 0; t < 4; t++) {
            #pragma unroll
            for (int nb = 0; nb < 4; nb++) {
                float v = acc16[nb][t];
                v = v > 0.f ? v : 0.f;
                uint32_t hb = rne_bf16(v);
                uint32_t pn2 = (uint32_t)__shfl_xor((int)hb, 1, 64);
                if (!(c & 1))
                    sHw[((c >> 4) * 4 + t) * 36 + nb * 8 + ((c & 15) >> 1)]
                        = hb | (pn2 << 16);
            }
        }
        asm volatile("s_waitcnt lgkmcnt(0)" ::: "memory");
        __builtin_amdgcn_sched_barrier(0);
        // wave-private epilogue: G = h x Wrel (hi/lo), R = h x Wroot + brel
        uint16_t* sGw = (uint16_t*)(smem + 2304);
        uint16_t* sRw = (uint16_t*)(smem + 2304 + 2176);
        int row = c & 15;
        int quad = c >> 4;
        int kb = quad * 8;
        bf16x8 ah0 = *(const bf16x8*)&sHw[row * 36 + quad * 4];
        bf16x8 ah1 = *(const bf16x8*)&sHw[row * 36 + 16 + quad * 4];
        #pragma unroll
        for (int ob = 0; ob < 4; ob++) {
            int oc = ob * 16 + row;
            {
                bf16x8 bh0 = *(const bf16x8*)&WgH[oc * 64 + kb];
                bf16x8 bh1 = *(const bf16x8*)&WgH[oc * 64 + 32 + kb];
                bf16x8 bl0 = *(const bf16x8*)&WgL[oc * 64 + kb];
                bf16x8 bl1 = *(const bf16x8*)&WgL[oc * 64 + 32 + kb];
                f32x4 acc = {0.f, 0.f, 0.f, 0.f};
                acc = __builtin_amdgcn_mfma_f32_16x16x32_bf16(ah0, bh0, acc, 0, 0, 0);
                acc = __builtin_amdgcn_mfma_f32_16x16x32_bf16(ah1, bh1, acc, 0, 0, 0);
                acc = __builtin_amdgcn_mfma_f32_16x16x32_bf16(ah0, bl0, acc, 0, 0, 0);
                acc = __builtin_amdgcn_mfma_f32_16x16x32_bf16(ah1, bl1, acc, 0, 0, 0);
                #pragma unroll
                for (int r = 0; r < 4; r++)
                    sGw[(quad * 4 + r) * 68 + oc] = (uint16_t)rne_bf16(acc[r]);
            }
            {
                bf16x8 bh0 = *(const bf16x8*)&WrH[oc * 64 + kb];
                bf16x8 bh1 = *(const bf16x8*)&WrH[oc * 64 + 32 + kb];
                bf16x8 bl0 = *(const bf16x8*)&WrL[oc * 64 + kb];
                bf16x8 bl1 = *(const bf16x8*)&WrL[oc * 64 + 32 + kb];
                float bias = brel[oc];
                f32x4 acc = {bias, bias, bias, bias};
                acc = __builtin_amdgcn_mfma_f32_16x16x32_bf16(ah0, bh0, acc, 0, 0, 0);
                acc = __builtin_amdgcn_mfma_f32_16x16x32_bf16(ah1, bh1, acc, 0, 0, 0);
                acc = __builtin_amdgcn_mfma_f32_16x16x32_bf16(ah0, bl0, acc, 0, 0, 0);
                acc = __builtin_amdgcn_mfma_f32_16x16x32_bf16(ah1, bl1, acc, 0, 0, 0);
                #pragma unroll
                for (int r = 0; r < 4; r++)
                    sRw[(quad * 4 + r) * 68 + oc] = (uint16_t)rne_bf16(acc[r]);
            }
        }
        asm volatile("s_waitcnt lgkmcnt(0)" ::: "memory");
        __builtin_amdgcn_sched_barrier(0);
        // write-out: 16 nodes x 32 dwords, 64 lanes -> 8 iters
        const uint32_t* sGd = (const uint32_t*)sGw;
        const uint32_t* sRd = (const uint32_t*)sRw;
        uint32_t* Gd = (uint32_t*)Gout;
        uint32_t* Rd = (uint32_t*)Rout;
        #pragma unroll
        for (int it = 0; it < 8; it++) {
            int idx = it * 64 + c;
            int nd = idx >> 5, col = idx & 31;
            int node = n0 + nd;
            if (node < NN) {
                Gd[node * 32 + col] = sGd[nd * 34 + col];
                Rd[node * 32 + col] = sRd[nd * 34 + col];
            }
        }
    } else {
        float wl[4], wo[4];
        #pragma unroll
        for (int nb = 0; nb < 4; nb++) {
            wl[nb] = WrelL[nb * 16 + (c & 15)];
            wo[nb] = WrootL[nb * 16 + (c & 15)];
        }
        #pragma unroll
        for (int t = 0; t < 4; t++) {
            float pa = 0.f, pr = 0.f;
            #pragma unroll
            for (int nb = 0; nb < 4; nb++) {
                float v = acc16[nb][t];
                v = v > 0.f ? v : 0.f;
                pa += v * wl[nb];
                pr += v * wo[nb];
            }
            #pragma unroll
            for (int o = 8; o > 0; o >>= 1) {
                pa += __shfl_down(pa, o, 64);
                pr += __shfl_down(pr, o, 64);
            }
            int node = n0 + (c >> 4) * 4 + t;
            if (!(c & 15) && node < NN) { sarr[node] = pa; rarr[node] = pr; }
        }
    }
}

// final edge pass: wave-per-4-nodes edge-parallel gather + shfl reduce
__global__ __launch_bounds__(256) void k_last(
        const int* __restrict__ offs, const int* __restrict__ ends,
        const uint32_t* __restrict__ pairs,
        const float* __restrict__ sarr, const float* __restrict__ rarr,
        const float* __restrict__ brelL, float* __restrict__ out) {
    int c = threadIdx.x & 63;
    int w = threadIdx.x >> 6;
    int blk16 = blockIdx.x * 16;
    float b0 = brelL[0];
    #pragma unroll
    for (int t = 0; t < 4; t++) {
        int node = blk16 + w * 4 + t;
        int b = offs[node], e = ends[node];
        float pp = 0.f;
        for (int j = b + c; j < e; j += 64) {
            uint32_t r = pairs[j];
            pp += __uint_as_float((r >> 17) << 16) * sarr[r & 0x1ffffu];
        }
        #pragma unroll
        for (int o = 32; o > 0; o >>= 1) pp += __shfl_down(pp, o, 64);
        if (c == 0) out[node] = pp + rarr[node] + b0;
    }
}

extern "C" void kernel_launch(void* const* d_in, const int* in_sizes, int n_in,
                              void* d_out, int out_size, void* d_ws, size_t ws_size,
                              hipStream_t stream) {
    const float* x        = (const float*)d_in[0];
    const int*   ei       = (const int*)d_in[1];
    const float* ew       = (const float*)d_in[2];
    const float* Wrel0    = (const float*)d_in[3];
    const float* brel0    = (const float*)d_in[4];
    const float* Wroot0   = (const float*)d_in[5];
    const float* Wrel_mid = (const float*)d_in[6];
    const float* brel_mid = (const float*)d_in[7];
    const float* Wroot_mid= (const float*)d_in[8];
    const float* WrelL    = (const float*)d_in[9];
    const float* brelL    = (const float*)d_in[10];
    const float* WrootL   = (const float*)d_in[11];
    float* out = (float*)d_out;

    const int* src  = ei;
    const int* dstp = ei + NE;

    char* w = (char*)d_ws;
    size_t o = 0;
    auto alloc = [&](size_t b) -> void* {
        void* r = (void*)(w + o);
        o += (b + 255) & ~(size_t)255;
        return r;
    };
    int*      offs  = (int*)alloc((size_t)NN * 4);
    int*      ends  = (int*)alloc((size_t)NN * 4);
    int*      bcur  = (int*)alloc((size_t)NBKT * 4);
    uint16_t* WgH   = (uint16_t*)alloc((size_t)3 * 4096 * 2);
    uint16_t* WgL   = (uint16_t*)alloc((size_t)3 * 4096 * 2);
    uint16_t* WrH   = (uint16_t*)alloc((size_t)3 * 4096 * 2);
    uint16_t* WrL   = (uint16_t*)alloc((size_t)3 * 4096 * 2);
    float*    sarr  = (float*)alloc((size_t)NN * 4);
    float*    rarr  = (float*)alloc((size_t)NN * 4);
    uint32_t* pairs = (uint32_t*)alloc((size_t)NBKT * CAP * 4);  // 12.8 MB padded
    uint16_t* GbA   = (uint16_t*)alloc((size_t)NN * HID * 2);    // 12.8 MB
    uint16_t* RbA   = (uint16_t*)alloc((size_t)NN * HID * 2);
    uint16_t* GbB   = (uint16_t*)alloc((size_t)NN * HID * 2);    // GbB/RbB contiguous
    uint16_t* RbB   = (uint16_t*)alloc((size_t)NN * HID * 2);
    (void)RbB;
    // bpairs (NBKT*CAP*8B = 25.6MB) aliases GbB+RbB (contiguous; dead before
    // mid layer 1 writes set B)
    int2*  bpairs = (int2*)GbB;

    // weight split + bucket cursor init (one launch)
    k_wsplit<<<(3 * 4096 + 255) / 256, 256, 0, stream>>>(
        Wrel_mid, Wroot_mid, WgH, WgL, WrH, WrL, bcur);

    // CSR build (padded buckets)
    k_bpart<<<NTILE, 256, 0, stream>>>(src, dstp, ew, bcur, bpairs);
    k_bcsr<<<NBKT, 256, 0, stream>>>(bcur, bpairs, offs, ends, pairs);

    // layer 0 (agg + transform + pre) -> G1,R1 (set A)
    k_l0pre<<<NN / 16, 256, 0, stream>>>(
        offs, ends, pairs, x, Wrel0, brel0, Wroot0,
        WgH, WgL, WrH, WrL, brel_mid, GbA, RbA);

    int nagg = (NN + 15) / 16;   // 6250 one-wave blocks, 16 nodes each
    // mid layer 1: consume set A, produce set B (weights index 1)
    k_aggfused<false><<<nagg, 64, 0, stream>>>(
        offs, ends, pairs, GbA, RbA,
        WgH + 4096, WgL + 4096, WrH + 4096, WrL + 4096, brel_mid + HID,
        GbB, RbB, WrelL, WrootL, sarr, rarr);
    // mid layer 2: consume set B, produce set A (weights index 2)
    k_aggfused<false><<<nagg, 64, 0, stream>>>(
        offs, ends, pairs, GbB, RbB,
        WgH + 2 * 4096, WgL + 2 * 4096, WrH + 2 * 4096, WrL + 2 * 4096,
        brel_mid + 2 * HID, GbA, RbA, WrelL, WrootL, sarr, rarr);
    // mid layer 3 (LAST): consume set A, produce s/r scalars
    k_aggfused<true><<<nagg, 64, 0, stream>>>(
        offs, ends, pairs, GbA, RbA,
        WgH, WgL, WrH, WrL, brel_mid,
        GbB, RbB, WrelL, WrootL, sarr, rarr);

    // final edge pass on scalars (16 nodes/block -> NN/16 blocks)
    k_last<<<NN / 16, 256, 0, stream>>>(offs, ends, pairs, sarr, rarr, brelL, out);
}